// Round 1
// baseline (1407.578 us; speedup 1.0000x reference)
//
#include <hip/hip_runtime.h>
#include <hip/hip_bf16.h>

// ---------------- problem constants ----------------
#define N_NODESC 10000
#define M_PAD    10112          // 79 * 128
#define NUM_GENE 2000
#define KPAD_G   2048
#define N_EDGESC 160000
#define E_TOT    170000         // + self loops
#define HEADS    10
#define F1       1280           // HEADS*128
#define LATENTC  128
#define LOWERC   64
#define CLUST    15

typedef __attribute__((ext_vector_type(8))) short   short8;   // bf16 frag (4 VGPR)
typedef __attribute__((ext_vector_type(4))) float   f32x4;
typedef __attribute__((ext_vector_type(4))) unsigned short ushort4_;

__device__ __forceinline__ float bf2f(unsigned short u){
    unsigned int x = ((unsigned int)u) << 16;
    return __builtin_bit_cast(float, x);
}
__device__ __forceinline__ unsigned short f2bf(float f){
    __hip_bfloat16 h = __float2bfloat16(f);           // RNE, compiler packs to cvt_pk
    return __builtin_bit_cast(unsigned short, h);
}

// ---------------- MFMA GEMM: C[M_pad x N] = A[M x K] * BT[N x K]^T ----------------
// AMODE: 0 = A is bf16 [lda pitch]; 1 = A is fp32; 2 = A is fp32 x + fp32 noise * rnorm[row]
// OMODE: 0 = bf16 out; 1 = f32 out.  Pad rows (>=M_real) are written as exact 0.
template<int AMODE, int OMODE, int BIAS, int RELU>
__global__ __launch_bounds__(256)
void gemm_bf16(const void* __restrict__ Ap, const float* __restrict__ noise,
               const float* __restrict__ rnorm,
               const unsigned short* __restrict__ BT, int ldb,
               const float* __restrict__ bias,
               void* __restrict__ Cp, int ldc,
               int M_real, int K, int lda)
{
    __shared__ short As[128*32];
    __shared__ short Bs[128*32];
    const int t  = threadIdx.x;
    const int bm = blockIdx.y, bn = blockIdx.x;
    const int wid = t >> 6, l = t & 63;
    const int wr = (wid >> 1) * 64, wc = (wid & 1) * 64;
    const int lrow = l & 15, lq = l >> 4;

    f32x4 acc[4][4] = {};
    const int KS = (K + 31) / 32;
    for (int ks = 0; ks < KS; ++ks) {
        const int kk = ks * 32;
        // ---- stage A (2 chunks of 8 bf16 per thread) ----
        #pragma unroll
        for (int cc = 0; cc < 2; ++cc) {
            int c = t + cc * 256;
            int row = c >> 2, slot = c & 3;
            int grow = bm * 128 + row;
            int gk = kk + slot * 8;
            short8 v = {};
            bool ok = (grow < M_real) && (gk < K);
            if constexpr (AMODE == 0) {
                if (ok) v = *(const short8*)((const unsigned short*)Ap + (size_t)grow * lda + gk);
            } else {
                if (ok) {
                    const float* A = (const float*)Ap;
                    f32x4 a0 = *(const f32x4*)(A + (size_t)grow * lda + gk);
                    f32x4 a1 = *(const f32x4*)(A + (size_t)grow * lda + gk + 4);
                    if constexpr (AMODE == 2) {
                        float rn = rnorm[grow];
                        f32x4 n0 = *(const f32x4*)(noise + (size_t)grow * lda + gk);
                        f32x4 n1 = *(const f32x4*)(noise + (size_t)grow * lda + gk + 4);
                        a0 = a0 + n0 * rn;
                        a1 = a1 + n1 * rn;
                    }
                    #pragma unroll
                    for (int i = 0; i < 4; ++i) { v[i] = (short)f2bf(a0[i]); v[4+i] = (short)f2bf(a1[i]); }
                }
            }
            *(short8*)(&As[row * 32 + ((slot ^ ((row >> 1) & 3)) << 3)]) = v;
        }
        // ---- stage B (BT rows = output cols, K contiguous, padded so no guard) ----
        #pragma unroll
        for (int cc = 0; cc < 2; ++cc) {
            int c = t + cc * 256;
            int row = c >> 2, slot = c & 3;
            int gn = bn * 128 + row;
            int gk = kk + slot * 8;
            short8 v = *(const short8*)(BT + (size_t)gn * ldb + gk);
            *(short8*)(&Bs[row * 32 + ((slot ^ ((row >> 1) & 3)) << 3)]) = v;
        }
        __syncthreads();
        // ---- fragments + 16 MFMA ----
        short8 af[4], bf_[4];
        #pragma unroll
        for (int mi = 0; mi < 4; ++mi) {
            int r = wr + mi * 16 + lrow;
            af[mi] = *(const short8*)(&As[r * 32 + ((lq ^ ((r >> 1) & 3)) << 3)]);
        }
        #pragma unroll
        for (int ni = 0; ni < 4; ++ni) {
            int r = wc + ni * 16 + lrow;
            bf_[ni] = *(const short8*)(&Bs[r * 32 + ((lq ^ ((r >> 1) & 3)) << 3)]);
        }
        #pragma unroll
        for (int mi = 0; mi < 4; ++mi)
            #pragma unroll
            for (int ni = 0; ni < 4; ++ni)
                acc[mi][ni] = __builtin_amdgcn_mfma_f32_16x16x32_bf16(af[mi], bf_[ni], acc[mi][ni], 0, 0, 0);
        __syncthreads();
    }
    // ---- epilogue: C/D layout col=lane&15, row=(lane>>4)*4+q  (m89 verified) ----
    #pragma unroll
    for (int mi = 0; mi < 4; ++mi) {
        #pragma unroll
        for (int ni = 0; ni < 4; ++ni) {
            int gcol = bn * 128 + wc + ni * 16 + lrow;
            #pragma unroll
            for (int q = 0; q < 4; ++q) {
                int grow = bm * 128 + wr + mi * 16 + lq * 4 + q;
                float val = acc[mi][ni][q];
                if constexpr (BIAS) val += bias[gcol];
                if constexpr (RELU) val = fmaxf(val, 0.f);
                if (grow >= M_real) val = 0.f;   // exact-zero pad rows
                if constexpr (OMODE == 0)
                    ((unsigned short*)Cp)[(size_t)grow * ldc + gcol] = f2bf(val);
                else
                    ((float*)Cp)[(size_t)grow * ldc + gcol] = val;
            }
        }
    }
}

// ---------------- noise row 1/||.|| ----------------
__global__ void rnorm_k(const float* __restrict__ noise, float* __restrict__ rn)
{
    int n = blockIdx.x, t = threadIdx.x;   // 256 threads
    const f32x4* p = (const f32x4*)(noise + (size_t)n * NUM_GENE);
    float acc = 0.f;
    for (int i = t; i < NUM_GENE / 4; i += 256) {
        f32x4 v = p[i];
        acc += v.x * v.x + v.y * v.y + v.z * v.z + v.w * v.w;
    }
    for (int off = 32; off; off >>= 1) acc += __shfl_down(acc, off);
    __shared__ float s[4];
    if ((t & 63) == 0) s[t >> 6] = acc;
    __syncthreads();
    if (t == 0) rn[n] = 1.f / fmaxf(sqrtf(s[0] + s[1] + s[2] + s[3]), 1e-12f);
}

// ---------------- transpose + fp32->bf16 (+K pad) : out[C][Kpad] = in[R][C]^T ----------------
__global__ void transpose_bf_k(const float* __restrict__ in, unsigned short* __restrict__ out,
                               int R, int C, int Kpad)
{
    __shared__ float tile[32][33];
    int tx = threadIdx.x & 31, ty = threadIdx.x >> 5;   // 256 threads
    int c0 = blockIdx.x * 32, r0 = blockIdx.y * 32;
    #pragma unroll
    for (int i = 0; i < 4; ++i) {
        int r = r0 + ty + i * 8, c = c0 + tx;
        tile[ty + i * 8][tx] = (r < R && c < C) ? in[(size_t)r * C + c] : 0.f;
    }
    __syncthreads();
    #pragma unroll
    for (int i = 0; i < 4; ++i) {
        int c = c0 + ty + i * 8;   // out row
        int r = r0 + tx;           // out col
        if (c < C && r < Kpad) out[(size_t)c * Kpad + r] = f2bf(tile[tx][ty + i * 8]);
    }
}

// ---------------- CSR build by dst ----------------
__global__ void hist_k(const int* __restrict__ ei, int* __restrict__ cnt)
{
    int e = blockIdx.x * 256 + threadIdx.x;
    if (e >= E_TOT) return;
    int d = (e < N_EDGESC) ? ei[N_EDGESC + e] : (e - N_EDGESC);
    atomicAdd(&cnt[d], 1);
}

__global__ void scan_k(const int* __restrict__ cnt, int* __restrict__ row_ptr, int* __restrict__ cursor)
{
    __shared__ int buf[1024];
    __shared__ int carry;
    int t = threadIdx.x;
    if (t == 0) carry = 0;
    __syncthreads();
    for (int ch = 0; ch < 10; ++ch) {
        int i = ch * 1024 + t;
        int v = (i < N_NODESC) ? cnt[i] : 0;
        buf[t] = v; __syncthreads();
        for (int off = 1; off < 1024; off <<= 1) {
            int tmp = (t >= off) ? buf[t - off] : 0;
            __syncthreads();
            buf[t] += tmp;
            __syncthreads();
        }
        int excl = buf[t] - v;
        int tot = buf[1023];
        if (i < N_NODESC) { row_ptr[i] = carry + excl; cursor[i] = carry + excl; }
        __syncthreads();
        if (t == 0) carry += tot;
        __syncthreads();
    }
    if (t == 0) row_ptr[N_NODESC] = carry;
}

__global__ void scatter_k(const int* __restrict__ ei, int* __restrict__ cursor, int* __restrict__ col_src)
{
    int e = blockIdx.x * 256 + threadIdx.x;
    if (e >= E_TOT) return;
    int s, d;
    if (e < N_EDGESC) { s = ei[e]; d = ei[N_EDGESC + e]; } else { s = d = e - N_EDGESC; }
    int pos = atomicAdd(&cursor[d], 1);
    col_src[pos] = s;
}

// ---------------- attention scores e_s,e_d [N,H] ----------------
__global__ void escores_k(const unsigned short* __restrict__ h,
                          const float* __restrict__ a_src, const float* __restrict__ a_dst,
                          float* __restrict__ e_s, float* __restrict__ e_d)
{
    int n = blockIdx.x, t = threadIdx.x;   // 128 threads
    __shared__ float sp[2], sd[2];
    for (int hh = 0; hh < HEADS; ++hh) {
        float v = bf2f(h[(size_t)n * F1 + hh * 128 + t]);
        float ps = v * a_src[hh * 128 + t];
        float pd = v * a_dst[hh * 128 + t];
        for (int off = 32; off; off >>= 1) { ps += __shfl_down(ps, off); pd += __shfl_down(pd, off); }
        if ((t & 63) == 0) { sp[t >> 6] = ps; sd[t >> 6] = pd; }
        __syncthreads();
        if (t == 0) { e_s[n * HEADS + hh] = sp[0] + sp[1]; e_d[n * HEADS + hh] = sd[0] + sd[1]; }
        __syncthreads();
    }
}

// ---------------- per-edge softmax weights ----------------
__global__ void edge_w_k(const int* __restrict__ row_ptr, const int* __restrict__ col_src,
                         const float* __restrict__ e_s, const float* __restrict__ e_d,
                         float* __restrict__ w_all)
{
    int gid = blockIdx.x * 256 + threadIdx.x;
    if (gid >= N_NODESC * HEADS) return;
    int n = gid / HEADS, hh = gid - n * HEADS;
    int beg = row_ptr[n], end = row_ptr[n + 1];
    float ed = e_d[n * HEADS + hh];
    float m = -1e30f;
    for (int e = beg; e < end; ++e) {
        float a = e_s[col_src[e] * HEADS + hh] + ed;
        a = a >= 0.f ? a : 0.2f * a;
        m = fmaxf(m, a);
    }
    float s = 0.f;
    for (int e = beg; e < end; ++e) {
        float a = e_s[col_src[e] * HEADS + hh] + ed;
        a = a >= 0.f ? a : 0.2f * a;
        s += __expf(a - m);
    }
    float inv = 1.f / s;
    for (int e = beg; e < end; ++e) {
        float a = e_s[col_src[e] * HEADS + hh] + ed;
        a = a >= 0.f ? a : 0.2f * a;
        w_all[(size_t)e * HEADS + hh] = __expf(a - m) * inv;
    }
}

// ---------------- layer1 aggregate (concat) + bias + relu -> bf16 ----------------
__global__ void agg1_k(const int* __restrict__ row_ptr, const int* __restrict__ col_src,
                       const float* __restrict__ w_all,
                       const unsigned short* __restrict__ h, const float* __restrict__ b1,
                       unsigned short* __restrict__ out)
{
    int n = blockIdx.x, t = threadIdx.x;   // 320 threads, 4 feats each
    int f0 = t * 4, hh = t >> 5;
    if (n >= N_NODESC) { ushort4_ z = {0,0,0,0}; *(ushort4_*)(out + (size_t)n * F1 + f0) = z; return; }
    int beg = row_ptr[n], end = row_ptr[n + 1];
    float a0 = 0.f, a1 = 0.f, a2 = 0.f, a3 = 0.f;
    for (int e = beg; e < end; ++e) {
        int s = col_src[e];
        float w = w_all[(size_t)e * HEADS + hh];
        ushort4_ r = *(const ushort4_*)(h + (size_t)s * F1 + f0);
        a0 += w * bf2f(r.x); a1 += w * bf2f(r.y); a2 += w * bf2f(r.z); a3 += w * bf2f(r.w);
    }
    ushort4_ o;
    o.x = f2bf(fmaxf(a0 + b1[f0 + 0], 0.f));
    o.y = f2bf(fmaxf(a1 + b1[f0 + 1], 0.f));
    o.z = f2bf(fmaxf(a2 + b1[f0 + 2], 0.f));
    o.w = f2bf(fmaxf(a3 + b1[f0 + 3], 0.f));
    *(ushort4_*)(out + (size_t)n * F1 + f0) = o;
}

// ---------------- layer2 aggregate (head mean) + bias + relu -> f32 ----------------
__global__ void agg2_k(const int* __restrict__ row_ptr, const int* __restrict__ col_src,
                       const float* __restrict__ w_all,
                       const unsigned short* __restrict__ h, const float* __restrict__ b2,
                       float* __restrict__ out)
{
    __shared__ float part[256];
    int n = blockIdx.x, t = threadIdx.x;   // 256 threads: 2 half-groups x 128 d
    int d = t & 127, hb = (t >> 7) * 5;
    float acc = 0.f;
    if (n < N_NODESC) {
        int beg = row_ptr[n], end = row_ptr[n + 1];
        for (int e = beg; e < end; ++e) {
            int s = col_src[e];
            const unsigned short* hp = h + (size_t)s * F1 + d;
            const float* wp = w_all + (size_t)e * HEADS + hb;
            #pragma unroll
            for (int j = 0; j < 5; ++j)
                acc += wp[j] * bf2f(hp[(hb + j) * 128]);
        }
    }
    part[t] = acc; __syncthreads();
    if (t < 128) {
        float v = (n < N_NODESC) ? fmaxf((part[t] + part[t + 128]) * 0.1f + b2[d], 0.f) : 0.f;
        out[(size_t)n * LATENTC + d] = v;
    }
}

// ---------------- column sums for pooling ----------------
__global__ void colsum_k(const float* __restrict__ g0, const float* __restrict__ g1,
                         const float* __restrict__ g2, float* __restrict__ gsum)
{
    int v = blockIdx.x / 40, b = blockIdx.x % 40;
    const float* src = (v == 0) ? g0 : (v == 1) ? g1 : g2;
    int t = threadIdx.x, col = t & 127, ro = t >> 7;
    int rend = min((b + 1) * 253, M_PAD);
    float acc = 0.f;
    for (int r = b * 253 + ro; r < rend; r += 2) acc += src[(size_t)r * 128 + col];
    __shared__ float part[256];
    part[t] = acc; __syncthreads();
    if (t < 128) atomicAdd(&gsum[v * 128 + col], part[t] + part[t + 128]);
}

// ---------------- contrastive loss scalar ----------------
__global__ void loss_k(const float* __restrict__ gsum, float* __restrict__ out)
{
    int t = threadIdx.x;   // 128
    float g0 = gsum[t] * 1e-4f, g1 = gsum[128 + t] * 1e-4f, g2 = gsum[256 + t] * 1e-4f;
    float d01 = g0 * g1, d02 = g0 * g2, d12 = g1 * g2;
    for (int off = 32; off; off >>= 1) {
        d01 += __shfl_down(d01, off); d02 += __shfl_down(d02, off); d12 += __shfl_down(d12, off);
    }
    __shared__ float s[3][2];
    if ((t & 63) == 0) { int w = t >> 6; s[0][w] = d01; s[1][w] = d02; s[2][w] = d12; }
    __syncthreads();
    if (t == 0) {
        float a01 = (s[0][0] + s[0][1]) * 5.f;   // /T, T=0.2
        float a02 = (s[1][0] + s[1][1]) * 5.f;
        float a12 = (s[2][0] + s[2][1]) * 5.f;
        float m = fmaxf(a01, fmaxf(a02, a12));
        float se = expf(a01 - m) + expf(a02 - m) + expf(a12 - m);
        *out = -((a01 - m) - logf(se)) / 2.302585092994046f;
    }
}

// ---------------- projection heads: out_node = gx@Wf+bf ; out_c = (gx@Wc+bc)^T ----------------
__global__ void proj_k(const float* __restrict__ gx,
                       const float* __restrict__ Wf, const float* __restrict__ bfv,
                       const float* __restrict__ Wc, const float* __restrict__ bc,
                       float* __restrict__ out_node, float* __restrict__ out_c)
{
    __shared__ float rowb[4][128];
    int wid = threadIdx.x >> 6, l = threadIdx.x & 63;
    int n = blockIdx.x * 4 + wid;
    if (n >= N_NODESC) return;
    rowb[wid][l]      = gx[(size_t)n * 128 + l];
    rowb[wid][l + 64] = gx[(size_t)n * 128 + 64 + l];
    // same-wave LDS, no barrier needed
    float acc = bfv[l];
    for (int k = 0; k < 128; ++k) acc += rowb[wid][k] * Wf[k * 64 + l];
    out_node[(size_t)n * 64 + l] = acc;
    if (out_c != nullptr && l < CLUST) {
        float a2 = bc[l];
        for (int k = 0; k < 128; ++k) a2 += rowb[wid][k] * Wc[k * CLUST + l];
        out_c[(size_t)l * N_NODESC + n] = a2;
    }
}

// ---------------- host ----------------
extern "C" void kernel_launch(void* const* d_in, const int* in_sizes, int n_in,
                              void* d_out, int out_size, void* d_ws, size_t ws_size,
                              hipStream_t stream)
{
    const float* x     = (const float*)d_in[0];
    const int*   ei    = (const int*)  d_in[1];
    const float* noise = (const float*)d_in[2];
    const float* W1    = (const float*)d_in[3];
    const float* a1s   = (const float*)d_in[4];
    const float* a1d   = (const float*)d_in[5];
    const float* b1    = (const float*)d_in[6];
    const float* W2    = (const float*)d_in[7];
    const float* a2s   = (const float*)d_in[8];
    const float* a2d   = (const float*)d_in[9];
    const float* b2    = (const float*)d_in[10];
    const float* Wm1   = (const float*)d_in[11];
    const float* bm1   = (const float*)d_in[12];
    const float* Wm2   = (const float*)d_in[13];
    const float* bm2   = (const float*)d_in[14];
    const float* Wf    = (const float*)d_in[15];
    const float* bfv   = (const float*)d_in[16];
    const float* Wc    = (const float*)d_in[17];
    const float* bc    = (const float*)d_in[18];
    float* out = (float*)d_out;

    // workspace carve-up (256B aligned)
    size_t off = 0;
    auto alloc = [&](size_t bytes) { size_t o = off; off = (off + bytes + 255) & ~(size_t)255; return o; };
    char* ws = (char*)d_ws;
    unsigned short* w1t   = (unsigned short*)(ws + alloc((size_t)F1 * KPAD_G * 2));
    unsigned short* w2t   = (unsigned short*)(ws + alloc((size_t)F1 * F1 * 2));
    unsigned short* wm1t  = (unsigned short*)(ws + alloc((size_t)128 * KPAD_G * 2));
    unsigned short* wm2t  = (unsigned short*)(ws + alloc((size_t)128 * 128 * 2));
    unsigned short* h_raw = (unsigned short*)(ws + alloc((size_t)M_PAD * F1 * 2));
    unsigned short* h1x   = (unsigned short*)(ws + alloc((size_t)M_PAD * F1 * 2));
    unsigned short* t_bf  = (unsigned short*)(ws + alloc((size_t)M_PAD * 128 * 2));
    float* es     = (float*)(ws + alloc((size_t)N_NODESC * HEADS * 4));
    float* ed     = (float*)(ws + alloc((size_t)N_NODESC * HEADS * 4));
    float* w_all  = (float*)(ws + alloc((size_t)E_TOT * HEADS * 4));
    int*   cnt    = (int*)  (ws + alloc((size_t)N_NODESC * 4));
    int*   rowp   = (int*)  (ws + alloc((size_t)(N_NODESC + 16) * 4));
    int*   cursor = (int*)  (ws + alloc((size_t)N_NODESC * 4));
    int*   colsrc = (int*)  (ws + alloc((size_t)E_TOT * 4));
    float* rnormp = (float*)(ws + alloc((size_t)N_NODESC * 4));
    float* gx     = (float*)(ws + alloc((size_t)M_PAD * 128 * 4));
    float* gx1    = (float*)(ws + alloc((size_t)M_PAD * 128 * 4));
    float* gx2    = (float*)(ws + alloc((size_t)M_PAD * 128 * 4));
    float* gsum   = (float*)(ws + alloc((size_t)384 * 4));
    (void)ws_size; (void)in_sizes; (void)n_in; (void)out_size;

    hipMemsetAsync(cnt, 0, (size_t)N_NODESC * 4, stream);
    hipMemsetAsync(gsum, 0, 384 * 4, stream);

    rnorm_k<<<N_NODESC, 256, 0, stream>>>(noise, rnormp);

    transpose_bf_k<<<dim3(40, 64), 256, 0, stream>>>(W1,  w1t,  NUM_GENE, F1,  KPAD_G);
    transpose_bf_k<<<dim3(40, 40), 256, 0, stream>>>(W2,  w2t,  F1,       F1,  F1);
    transpose_bf_k<<<dim3(4, 64),  256, 0, stream>>>(Wm1, wm1t, NUM_GENE, 128, KPAD_G);
    transpose_bf_k<<<dim3(4, 4),   256, 0, stream>>>(Wm2, wm2t, 128,      128, 128);

    hist_k   <<<(E_TOT + 255) / 256, 256, 0, stream>>>(ei, cnt);
    scan_k   <<<1, 1024, 0, stream>>>(cnt, rowp, cursor);
    scatter_k<<<(E_TOT + 255) / 256, 256, 0, stream>>>(ei, cursor, colsrc);

    for (int p = 0; p < 2; ++p) {
        if (p == 0)
            gemm_bf16<1,0,0,0><<<dim3(10, 79), 256, 0, stream>>>(x, nullptr, nullptr, w1t, KPAD_G,
                nullptr, h_raw, F1, N_NODESC, NUM_GENE, NUM_GENE);
        else
            gemm_bf16<2,0,0,0><<<dim3(10, 79), 256, 0, stream>>>(x, noise, rnormp, w1t, KPAD_G,
                nullptr, h_raw, F1, N_NODESC, NUM_GENE, NUM_GENE);
        escores_k<<<N_NODESC, 128, 0, stream>>>(h_raw, a1s, a1d, es, ed);
        edge_w_k <<<(N_NODESC * HEADS + 255) / 256, 256, 0, stream>>>(rowp, colsrc, es, ed, w_all);
        agg1_k   <<<M_PAD, 320, 0, stream>>>(rowp, colsrc, w_all, h_raw, b1, h1x);
        gemm_bf16<0,0,0,0><<<dim3(10, 79), 256, 0, stream>>>(h1x, nullptr, nullptr, w2t, F1,
            nullptr, h_raw, F1, N_NODESC, F1, F1);
        escores_k<<<N_NODESC, 128, 0, stream>>>(h_raw, a2s, a2d, es, ed);
        edge_w_k <<<(N_NODESC * HEADS + 255) / 256, 256, 0, stream>>>(rowp, colsrc, es, ed, w_all);
        agg2_k   <<<M_PAD, 256, 0, stream>>>(rowp, colsrc, w_all, h_raw, b2, p == 0 ? gx : gx1);
    }

    // MLP branch
    gemm_bf16<1,0,1,1><<<dim3(1, 79), 256, 0, stream>>>(x, nullptr, nullptr, wm1t, KPAD_G,
        bm1, t_bf, 128, N_NODESC, NUM_GENE, NUM_GENE);
    gemm_bf16<0,1,1,0><<<dim3(1, 79), 256, 0, stream>>>(t_bf, nullptr, nullptr, wm2t, 128,
        bm2, gx2, 128, N_NODESC, 128, 128);

    colsum_k<<<120, 256, 0, stream>>>(gx, gx1, gx2, gsum);
    loss_k  <<<1, 128, 0, stream>>>(gsum, out + 1920000);

    proj_k<<<2500, 256, 0, stream>>>(gx,  Wf, bfv, Wc, bc, out,           out + 1920001);
    proj_k<<<2500, 256, 0, stream>>>(gx1, Wf, bfv, Wc, bc, out + 640000,  out + 2070001);
    proj_k<<<2500, 256, 0, stream>>>(gx2, Wf, bfv, nullptr, nullptr, out + 1280000, nullptr);
}

// Round 2
// 1132.647 us; speedup vs baseline: 1.2427x; 1.2427x over previous
//
#include <hip/hip_runtime.h>
#include <hip/hip_bf16.h>

// ---------------- problem constants ----------------
#define N_NODESC 10000
#define M_PAD    10112          // 79 * 128
#define RT_TILES 79
#define NUM_GENE 2000
#define KPAD_G   2048
#define N_EDGESC 160000
#define E_TOT    170000         // + self loops
#define HEADS    10
#define F1       1280           // HEADS*128
#define LATENTC  128
#define LOWERC   64
#define CLUST    15

typedef __attribute__((ext_vector_type(8))) short   short8;   // bf16 frag (4 VGPR)
typedef __attribute__((ext_vector_type(4))) float   f32x4;
typedef __attribute__((ext_vector_type(4))) unsigned short ushort4_;

__device__ __forceinline__ float bf2f(unsigned short u){
    unsigned int x = ((unsigned int)u) << 16;
    return __builtin_bit_cast(float, x);
}
__device__ __forceinline__ unsigned short f2bf(float f){
    __hip_bfloat16 h = __float2bfloat16(f);
    return __builtin_bit_cast(unsigned short, h);
}

// async global->LDS, 16B per lane; LDS dest = wave-uniform base + lane*16
__device__ __forceinline__ void gload16(const void* g, void* l) {
    __builtin_amdgcn_global_load_lds((const __attribute__((address_space(1))) void*)g,
                                     (__attribute__((address_space(3))) void*)l, 16, 0, 0);
}

// ---------------- bf16 MFMA GEMM, global_load_lds staging, XCD-chunked swizzle ----
// C[M_PAD x N] = A[M_PAD x K](bf16,row-major,zero-padded) * BT[N x K]^T (bf16)
// K = KT*32 exactly; N = NT*128 exactly; grid = RT_TILES * NT (1-D).
// LDS layout per 128x32 tile: linear chunks; global source pre-XOR-swizzled so that
// ds_read at slot (lq ^ ((r>>1)&3)) returns global slot lq  (rule 21, conflict-free).
template<int OMODE, int BIAS, int RELU>   // OMODE 0=bf16 out, 1=f32 out
__global__ __launch_bounds__(256)
void gemm2(const unsigned short* __restrict__ A, int lda,
           const unsigned short* __restrict__ BT, int ldb,
           const float* __restrict__ bias,
           void* __restrict__ Cp, int ldc,
           int KT, int NT, int M_real)
{
    __shared__ short smem[8192];           // As[4096] + Bs[4096]  (16 KiB)
    short* As = smem;
    short* Bs = smem + 4096;

    // bijective chunked XCD swizzle (m204): consecutive wgid -> same XCD chunk
    const int nwg = gridDim.x;
    const int q = nwg >> 3, r = nwg & 7;
    const int xcd = blockIdx.x & 7, idx = blockIdx.x >> 3;
    const int wgid = (xcd < r ? xcd * (q + 1) : r * (q + 1) + (xcd - r) * q) + idx;
    const int bm = wgid / NT, bn = wgid - bm * NT;   // bn fastest within chunk -> A reuse in L2

    const int t = threadIdx.x, w = t >> 6, lane = t & 63;
    const int wr = (w >> 1) * 64, wc = (w & 1) * 64;
    const int lrow = lane & 15, lq = lane >> 4;

    // per-thread staging addresses (2 chunks of 16B each for A and B)
    const unsigned short* Ag[2];
    const unsigned short* Bg[2];
    int lds_off[2];                         // in shorts
    #pragma unroll
    for (int cc = 0; cc < 2; ++cc) {
        int c = cc * 256 + t;               // chunk 0..511
        int row = c >> 2, slot = c & 3;
        int gk = (slot ^ ((row >> 1) & 3)) << 3;   // pre-swizzled global k offset
        Ag[cc] = A  + (size_t)(bm * 128 + row) * lda + gk;
        Bg[cc] = BT + (size_t)(bn * 128 + row) * ldb + gk;
        lds_off[cc] = cc * 2048 + w * 512 + lane * 8;  // linear: chunk*8 shorts
    }

    f32x4 acc[4][4] = {};
    for (int kt = 0; kt < KT; ++kt) {
        const int kk = kt * 32;
        #pragma unroll
        for (int cc = 0; cc < 2; ++cc) {
            gload16(Ag[cc] + kk, As + lds_off[cc]);
            gload16(Bg[cc] + kk, Bs + lds_off[cc]);
        }
        __syncthreads();                    // compiler drains vmcnt before barrier
        short8 af[4], bf_[4];
        #pragma unroll
        for (int mi = 0; mi < 4; ++mi) {
            int rr = wr + mi * 16 + lrow;
            af[mi] = *(const short8*)(&As[rr * 32 + ((lq ^ ((rr >> 1) & 3)) << 3)]);
        }
        #pragma unroll
        for (int ni = 0; ni < 4; ++ni) {
            int rr = wc + ni * 16 + lrow;
            bf_[ni] = *(const short8*)(&Bs[rr * 32 + ((lq ^ ((rr >> 1) & 3)) << 3)]);
        }
        #pragma unroll
        for (int mi = 0; mi < 4; ++mi)
            #pragma unroll
            for (int ni = 0; ni < 4; ++ni)
                acc[mi][ni] = __builtin_amdgcn_mfma_f32_16x16x32_bf16(af[mi], bf_[ni], acc[mi][ni], 0, 0, 0);
        __syncthreads();
    }

    // epilogue: C/D layout col=lane&15, row=(lane>>4)*4+q (m89 verified)
    #pragma unroll
    for (int mi = 0; mi < 4; ++mi) {
        #pragma unroll
        for (int ni = 0; ni < 4; ++ni) {
            int gcol = bn * 128 + wc + ni * 16 + lrow;
            #pragma unroll
            for (int qq = 0; qq < 4; ++qq) {
                int grow = bm * 128 + wr + mi * 16 + lq * 4 + qq;
                float val = acc[mi][ni][qq];
                if constexpr (BIAS) val += bias[gcol];
                if constexpr (RELU) val = fmaxf(val, 0.f);
                if (grow >= M_real) val = 0.f;
                if constexpr (OMODE == 0)
                    ((unsigned short*)Cp)[(size_t)grow * ldc + gcol] = f2bf(val);
                else
                    ((float*)Cp)[(size_t)grow * ldc + gcol] = val;
            }
        }
    }
}

// ---------------- noise row 1/||.|| ----------------
__global__ void rnorm_k(const float* __restrict__ noise, float* __restrict__ rn)
{
    int n = blockIdx.x, t = threadIdx.x;   // 256 threads
    const f32x4* p = (const f32x4*)(noise + (size_t)n * NUM_GENE);
    float acc = 0.f;
    for (int i = t; i < NUM_GENE / 4; i += 256) {
        f32x4 v = p[i];
        acc += v.x * v.x + v.y * v.y + v.z * v.z + v.w * v.w;
    }
    for (int off = 32; off; off >>= 1) acc += __shfl_down(acc, off);
    __shared__ float s[4];
    if ((t & 63) == 0) s[t >> 6] = acc;
    __syncthreads();
    if (t == 0) rn[n] = 1.f / fmaxf(sqrtf(s[0] + s[1] + s[2] + s[3]), 1e-12f);
}

// ---------------- fp32 -> bf16 conversion, [M_PAD][KPAD_G], zero-padded ----------------
// AUG=0: out = bf16(x); AUG=1: out = bf16(x + noise * rn[row])
template<int AUG>
__global__ void convert_k(const float* __restrict__ x, const float* __restrict__ noise,
                          const float* __restrict__ rn, unsigned short* __restrict__ out)
{
    int gid = blockIdx.x * 256 + threadIdx.x;     // one thread = 8 elems
    int row = gid >> 8, kc = (gid & 255) * 8;     // KPAD_G/8 = 256 chunks per row
    if (row >= M_PAD) return;
    short8 v = {};
    if (row < N_NODESC && kc < NUM_GENE) {        // NUM_GENE = 250*8, chunks fully in/out
        f32x4 a0 = *(const f32x4*)(x + (size_t)row * NUM_GENE + kc);
        f32x4 a1 = *(const f32x4*)(x + (size_t)row * NUM_GENE + kc + 4);
        if constexpr (AUG) {
            float r = rn[row];
            f32x4 n0 = *(const f32x4*)(noise + (size_t)row * NUM_GENE + kc);
            f32x4 n1 = *(const f32x4*)(noise + (size_t)row * NUM_GENE + kc + 4);
            a0 = a0 + n0 * r;
            a1 = a1 + n1 * r;
        }
        #pragma unroll
        for (int i = 0; i < 4; ++i) { v[i] = (short)f2bf(a0[i]); v[4 + i] = (short)f2bf(a1[i]); }
    }
    *(short8*)(out + (size_t)row * KPAD_G + kc) = v;
}

// ---------------- transpose + fp32->bf16 (+K pad) : out[C][Kpad] = in[R][C]^T ----------------
__global__ void transpose_bf_k(const float* __restrict__ in, unsigned short* __restrict__ out,
                               int R, int C, int Kpad)
{
    __shared__ float tile[32][33];
    int tx = threadIdx.x & 31, ty = threadIdx.x >> 5;   // 256 threads
    int c0 = blockIdx.x * 32, r0 = blockIdx.y * 32;
    #pragma unroll
    for (int i = 0; i < 4; ++i) {
        int r = r0 + ty + i * 8, c = c0 + tx;
        tile[ty + i * 8][tx] = (r < R && c < C) ? in[(size_t)r * C + c] : 0.f;
    }
    __syncthreads();
    #pragma unroll
    for (int i = 0; i < 4; ++i) {
        int c = c0 + ty + i * 8;   // out row
        int r = r0 + tx;           // out col
        if (c < C && r < Kpad) out[(size_t)c * Kpad + r] = f2bf(tile[tx][ty + i * 8]);
    }
}

// ---------------- CSR build by dst ----------------
__global__ void hist_k(const int* __restrict__ ei, int* __restrict__ cnt)
{
    int e = blockIdx.x * 256 + threadIdx.x;
    if (e >= E_TOT) return;
    int d = (e < N_EDGESC) ? ei[N_EDGESC + e] : (e - N_EDGESC);
    atomicAdd(&cnt[d], 1);
}

__global__ void scan_k(const int* __restrict__ cnt, int* __restrict__ row_ptr, int* __restrict__ cursor)
{
    __shared__ int buf[1024];
    __shared__ int carry;
    int t = threadIdx.x;
    if (t == 0) carry = 0;
    __syncthreads();
    for (int ch = 0; ch < 10; ++ch) {
        int i = ch * 1024 + t;
        int v = (i < N_NODESC) ? cnt[i] : 0;
        buf[t] = v; __syncthreads();
        for (int off = 1; off < 1024; off <<= 1) {
            int tmp = (t >= off) ? buf[t - off] : 0;
            __syncthreads();
            buf[t] += tmp;
            __syncthreads();
        }
        int excl = buf[t] - v;
        int tot = buf[1023];
        if (i < N_NODESC) { row_ptr[i] = carry + excl; cursor[i] = carry + excl; }
        __syncthreads();
        if (t == 0) carry += tot;
        __syncthreads();
    }
    if (t == 0) row_ptr[N_NODESC] = carry;
}

__global__ void scatter_k(const int* __restrict__ ei, int* __restrict__ cursor, int* __restrict__ col_src)
{
    int e = blockIdx.x * 256 + threadIdx.x;
    if (e >= E_TOT) return;
    int s, d;
    if (e < N_EDGESC) { s = ei[e]; d = ei[N_EDGESC + e]; } else { s = d = e - N_EDGESC; }
    int pos = atomicAdd(&cursor[d], 1);
    col_src[pos] = s;
}

// ---------------- attention scores e_s,e_d [N,H] ----------------
__global__ void escores_k(const unsigned short* __restrict__ h,
                          const float* __restrict__ a_src, const float* __restrict__ a_dst,
                          float* __restrict__ e_s, float* __restrict__ e_d)
{
    int n = blockIdx.x, t = threadIdx.x;   // 128 threads
    __shared__ float sp[2], sd[2];
    for (int hh = 0; hh < HEADS; ++hh) {
        float v = bf2f(h[(size_t)n * F1 + hh * 128 + t]);
        float ps = v * a_src[hh * 128 + t];
        float pd = v * a_dst[hh * 128 + t];
        for (int off = 32; off; off >>= 1) { ps += __shfl_down(ps, off); pd += __shfl_down(pd, off); }
        if ((t & 63) == 0) { sp[t >> 6] = ps; sd[t >> 6] = pd; }
        __syncthreads();
        if (t == 0) { e_s[n * HEADS + hh] = sp[0] + sp[1]; e_d[n * HEADS + hh] = sd[0] + sd[1]; }
        __syncthreads();
    }
}

// ---------------- per-edge softmax weights ----------------
__global__ void edge_w_k(const int* __restrict__ row_ptr, const int* __restrict__ col_src,
                         const float* __restrict__ e_s, const float* __restrict__ e_d,
                         float* __restrict__ w_all)
{
    int gid = blockIdx.x * 256 + threadIdx.x;
    if (gid >= N_NODESC * HEADS) return;
    int n = gid / HEADS, hh = gid - n * HEADS;
    int beg = row_ptr[n], end = row_ptr[n + 1];
    float ed = e_d[n * HEADS + hh];
    float m = -1e30f;
    for (int e = beg; e < end; ++e) {
        float a = e_s[col_src[e] * HEADS + hh] + ed;
        a = a >= 0.f ? a : 0.2f * a;
        m = fmaxf(m, a);
    }
    float s = 0.f;
    for (int e = beg; e < end; ++e) {
        float a = e_s[col_src[e] * HEADS + hh] + ed;
        a = a >= 0.f ? a : 0.2f * a;
        s += __expf(a - m);
    }
    float inv = 1.f / s;
    for (int e = beg; e < end; ++e) {
        float a = e_s[col_src[e] * HEADS + hh] + ed;
        a = a >= 0.f ? a : 0.2f * a;
        w_all[(size_t)e * HEADS + hh] = __expf(a - m) * inv;
    }
}

// ---------------- layer1 aggregate (concat) + bias + relu -> bf16 ----------------
__global__ void agg1_k(const int* __restrict__ row_ptr, const int* __restrict__ col_src,
                       const float* __restrict__ w_all,
                       const unsigned short* __restrict__ h, const float* __restrict__ b1,
                       unsigned short* __restrict__ out)
{
    int n = blockIdx.x, t = threadIdx.x;   // 320 threads, 4 feats each
    int f0 = t * 4, hh = t >> 5;
    if (n >= N_NODESC) { ushort4_ z = {0,0,0,0}; *(ushort4_*)(out + (size_t)n * F1 + f0) = z; return; }
    int beg = row_ptr[n], end = row_ptr[n + 1];
    float a0 = 0.f, a1 = 0.f, a2 = 0.f, a3 = 0.f;
    for (int e = beg; e < end; ++e) {
        int s = col_src[e];
        float w = w_all[(size_t)e * HEADS + hh];
        ushort4_ r = *(const ushort4_*)(h + (size_t)s * F1 + f0);
        a0 += w * bf2f(r.x); a1 += w * bf2f(r.y); a2 += w * bf2f(r.z); a3 += w * bf2f(r.w);
    }
    ushort4_ o;
    o.x = f2bf(fmaxf(a0 + b1[f0 + 0], 0.f));
    o.y = f2bf(fmaxf(a1 + b1[f0 + 1], 0.f));
    o.z = f2bf(fmaxf(a2 + b1[f0 + 2], 0.f));
    o.w = f2bf(fmaxf(a3 + b1[f0 + 3], 0.f));
    *(ushort4_*)(out + (size_t)n * F1 + f0) = o;
}

// ---------------- layer2 aggregate (head mean) + bias + relu -> f32 ----------------
__global__ void agg2_k(const int* __restrict__ row_ptr, const int* __restrict__ col_src,
                       const float* __restrict__ w_all,
                       const unsigned short* __restrict__ h, const float* __restrict__ b2,
                       float* __restrict__ out)
{
    __shared__ float part[256];
    int n = blockIdx.x, t = threadIdx.x;   // 256 threads: 2 half-groups x 128 d
    int d = t & 127, hb = (t >> 7) * 5;
    float acc = 0.f;
    if (n < N_NODESC) {
        int beg = row_ptr[n], end = row_ptr[n + 1];
        for (int e = beg; e < end; ++e) {
            int s = col_src[e];
            const unsigned short* hp = h + (size_t)s * F1 + d;
            const float* wp = w_all + (size_t)e * HEADS + hb;
            #pragma unroll
            for (int j = 0; j < 5; ++j)
                acc += wp[j] * bf2f(hp[(hb + j) * 128]);
        }
    }
    part[t] = acc; __syncthreads();
    if (t < 128) {
        float v = (n < N_NODESC) ? fmaxf((part[t] + part[t + 128]) * 0.1f + b2[d], 0.f) : 0.f;
        out[(size_t)n * LATENTC + d] = v;
    }
}

// ---------------- column sums for pooling ----------------
__global__ void colsum_k(const float* __restrict__ g0, const float* __restrict__ g1,
                         const float* __restrict__ g2, float* __restrict__ gsum)
{
    int v = blockIdx.x / 40, b = blockIdx.x % 40;
    const float* src = (v == 0) ? g0 : (v == 1) ? g1 : g2;
    int t = threadIdx.x, col = t & 127, ro = t >> 7;
    int rend = min((b + 1) * 253, M_PAD);
    float acc = 0.f;
    for (int r = b * 253 + ro; r < rend; r += 2) acc += src[(size_t)r * 128 + col];
    __shared__ float part[256];
    part[t] = acc; __syncthreads();
    if (t < 128) atomicAdd(&gsum[v * 128 + col], part[t] + part[t + 128]);
}

// ---------------- contrastive loss scalar ----------------
__global__ void loss_k(const float* __restrict__ gsum, float* __restrict__ out)
{
    int t = threadIdx.x;   // 128
    float g0 = gsum[t] * 1e-4f, g1 = gsum[128 + t] * 1e-4f, g2 = gsum[256 + t] * 1e-4f;
    float d01 = g0 * g1, d02 = g0 * g2, d12 = g1 * g2;
    for (int off = 32; off; off >>= 1) {
        d01 += __shfl_down(d01, off); d02 += __shfl_down(d02, off); d12 += __shfl_down(d12, off);
    }
    __shared__ float s[3][2];
    if ((t & 63) == 0) { int w = t >> 6; s[0][w] = d01; s[1][w] = d02; s[2][w] = d12; }
    __syncthreads();
    if (t == 0) {
        float a01 = (s[0][0] + s[0][1]) * 5.f;   // /T, T=0.2
        float a02 = (s[1][0] + s[1][1]) * 5.f;
        float a12 = (s[2][0] + s[2][1]) * 5.f;
        float m = fmaxf(a01, fmaxf(a02, a12));
        float se = expf(a01 - m) + expf(a02 - m) + expf(a12 - m);
        *out = -((a01 - m) - logf(se)) / 2.302585092994046f;
    }
}

// ---------------- projection heads ----------------
__global__ void proj_k(const float* __restrict__ gx,
                       const float* __restrict__ Wf, const float* __restrict__ bfv,
                       const float* __restrict__ Wc, const float* __restrict__ bc,
                       float* __restrict__ out_node, float* __restrict__ out_c)
{
    __shared__ float rowb[4][128];
    int wid = threadIdx.x >> 6, l = threadIdx.x & 63;
    int n = blockIdx.x * 4 + wid;
    if (n >= N_NODESC) return;
    rowb[wid][l]      = gx[(size_t)n * 128 + l];
    rowb[wid][l + 64] = gx[(size_t)n * 128 + 64 + l];
    float acc = bfv[l];
    for (int k = 0; k < 128; ++k) acc += rowb[wid][k] * Wf[k * 64 + l];
    out_node[(size_t)n * 64 + l] = acc;
    if (out_c != nullptr && l < CLUST) {
        float a2 = bc[l];
        for (int k = 0; k < 128; ++k) a2 += rowb[wid][k] * Wc[k * CLUST + l];
        out_c[(size_t)l * N_NODESC + n] = a2;
    }
}

// ---------------- host ----------------
extern "C" void kernel_launch(void* const* d_in, const int* in_sizes, int n_in,
                              void* d_out, int out_size, void* d_ws, size_t ws_size,
                              hipStream_t stream)
{
    const float* x     = (const float*)d_in[0];
    const int*   ei    = (const int*)  d_in[1];
    const float* noise = (const float*)d_in[2];
    const float* W1    = (const float*)d_in[3];
    const float* a1s   = (const float*)d_in[4];
    const float* a1d   = (const float*)d_in[5];
    const float* b1    = (const float*)d_in[6];
    const float* W2    = (const float*)d_in[7];
    const float* a2s   = (const float*)d_in[8];
    const float* a2d   = (const float*)d_in[9];
    const float* b2    = (const float*)d_in[10];
    const float* Wm1   = (const float*)d_in[11];
    const float* bm1   = (const float*)d_in[12];
    const float* Wm2   = (const float*)d_in[13];
    const float* bm2   = (const float*)d_in[14];
    const float* Wf    = (const float*)d_in[15];
    const float* bfv   = (const float*)d_in[16];
    const float* Wc    = (const float*)d_in[17];
    const float* bc    = (const float*)d_in[18];
    float* out = (float*)d_out;

    size_t off = 0;
    auto alloc = [&](size_t bytes) { size_t o = off; off = (off + bytes + 255) & ~(size_t)255; return o; };
    char* ws = (char*)d_ws;
    unsigned short* w1t   = (unsigned short*)(ws + alloc((size_t)F1 * KPAD_G * 2));
    unsigned short* w2t   = (unsigned short*)(ws + alloc((size_t)F1 * F1 * 2));
    unsigned short* wm1t  = (unsigned short*)(ws + alloc((size_t)128 * KPAD_G * 2));
    unsigned short* wm2t  = (unsigned short*)(ws + alloc((size_t)128 * 128 * 2));
    unsigned short* h_raw = (unsigned short*)(ws + alloc((size_t)M_PAD * F1 * 2));
    unsigned short* h1x   = (unsigned short*)(ws + alloc((size_t)M_PAD * F1 * 2));
    unsigned short* t_bf  = (unsigned short*)(ws + alloc((size_t)M_PAD * 128 * 2));
    unsigned short* xbuf  = (unsigned short*)(ws + alloc((size_t)M_PAD * KPAD_G * 2));  // xb, then x_aug
    float* es     = (float*)(ws + alloc((size_t)N_NODESC * HEADS * 4));
    float* ed     = (float*)(ws + alloc((size_t)N_NODESC * HEADS * 4));
    float* w_all  = (float*)(ws + alloc((size_t)E_TOT * HEADS * 4));
    int*   cnt    = (int*)  (ws + alloc((size_t)N_NODESC * 4));
    int*   rowp   = (int*)  (ws + alloc((size_t)(N_NODESC + 16) * 4));
    int*   cursor = (int*)  (ws + alloc((size_t)N_NODESC * 4));
    int*   colsrc = (int*)  (ws + alloc((size_t)E_TOT * 4));
    float* rnormp = (float*)(ws + alloc((size_t)N_NODESC * 4));
    float* gx     = (float*)(ws + alloc((size_t)M_PAD * 128 * 4));
    float* gx1    = (float*)(ws + alloc((size_t)M_PAD * 128 * 4));
    float* gx2    = (float*)(ws + alloc((size_t)M_PAD * 128 * 4));
    float* gsum   = (float*)(ws + alloc((size_t)384 * 4));
    (void)ws_size; (void)in_sizes; (void)n_in; (void)out_size;

    hipMemsetAsync(cnt, 0, (size_t)N_NODESC * 4, stream);
    hipMemsetAsync(gsum, 0, 384 * 4, stream);

    rnorm_k<<<N_NODESC, 256, 0, stream>>>(noise, rnormp);
    convert_k<0><<<M_PAD, 256, 0, stream>>>(x, nullptr, nullptr, xbuf);

    transpose_bf_k<<<dim3(40, 64), 256, 0, stream>>>(W1,  w1t,  NUM_GENE, F1,  KPAD_G);
    transpose_bf_k<<<dim3(40, 40), 256, 0, stream>>>(W2,  w2t,  F1,       F1,  F1);
    transpose_bf_k<<<dim3(4, 64),  256, 0, stream>>>(Wm1, wm1t, NUM_GENE, 128, KPAD_G);
    transpose_bf_k<<<dim3(4, 4),   256, 0, stream>>>(Wm2, wm2t, 128,      128, 128);

    hist_k   <<<(E_TOT + 255) / 256, 256, 0, stream>>>(ei, cnt);
    scan_k   <<<1, 1024, 0, stream>>>(cnt, rowp, cursor);
    scatter_k<<<(E_TOT + 255) / 256, 256, 0, stream>>>(ei, cursor, colsrc);

    // MLP branch first (uses xbuf before it is overwritten with x_aug)
    gemm2<0,1,1><<<RT_TILES * 1, 256, 0, stream>>>(xbuf, KPAD_G, wm1t, KPAD_G,
        bm1, t_bf, 128, 64, 1, N_NODESC);
    gemm2<1,1,0><<<RT_TILES * 1, 256, 0, stream>>>(t_bf, 128, wm2t, 128,
        bm2, gx2, 128, 4, 1, N_NODESC);

    for (int p = 0; p < 2; ++p) {
        if (p == 1)
            convert_k<1><<<M_PAD, 256, 0, stream>>>(x, noise, rnormp, xbuf);
        gemm2<0,0,0><<<RT_TILES * 10, 256, 0, stream>>>(xbuf, KPAD_G, w1t, KPAD_G,
            nullptr, h_raw, F1, 64, 10, N_NODESC);
        escores_k<<<N_NODESC, 128, 0, stream>>>(h_raw, a1s, a1d, es, ed);
        edge_w_k <<<(N_NODESC * HEADS + 255) / 256, 256, 0, stream>>>(rowp, colsrc, es, ed, w_all);
        agg1_k   <<<M_PAD, 320, 0, stream>>>(rowp, colsrc, w_all, h_raw, b1, h1x);
        gemm2<0,0,0><<<RT_TILES * 10, 256, 0, stream>>>(h1x, F1, w2t, F1,
            nullptr, h_raw, F1, 40, 10, N_NODESC);
        escores_k<<<N_NODESC, 128, 0, stream>>>(h_raw, a2s, a2d, es, ed);
        edge_w_k <<<(N_NODESC * HEADS + 255) / 256, 256, 0, stream>>>(rowp, colsrc, es, ed, w_all);
        agg2_k   <<<M_PAD, 256, 0, stream>>>(rowp, colsrc, w_all, h_raw, b2, p == 0 ? gx : gx1);
    }

    colsum_k<<<120, 256, 0, stream>>>(gx, gx1, gx2, gsum);
    loss_k  <<<1, 128, 0, stream>>>(gsum, out + 1920000);

    proj_k<<<2500, 256, 0, stream>>>(gx,  Wf, bfv, Wc, bc, out,           out + 1920001);
    proj_k<<<2500, 256, 0, stream>>>(gx1, Wf, bfv, Wc, bc, out + 640000,  out + 2070001);
    proj_k<<<2500, 256, 0, stream>>>(gx2, Wf, bfv, nullptr, nullptr, out + 1280000, nullptr);
}

// Round 3
// 948.178 us; speedup vs baseline: 1.4845x; 1.1946x over previous
//
#include <hip/hip_runtime.h>
#include <hip/hip_bf16.h>

// ---------------- problem constants ----------------
#define N_NODESC 10000
#define M_PAD    10112          // 79 * 128
#define RT_TILES 79
#define NUM_GENE 2000
#define KPAD_G   2048
#define N_EDGESC 160000
#define E_TOT    170000         // + self loops
#define HEADS    10
#define F1       1280           // HEADS*128
#define LATENTC  128
#define LOWERC   64
#define CLUST    15

typedef __attribute__((ext_vector_type(8))) short   short8;   // bf16 frag (4 VGPR)
typedef __attribute__((ext_vector_type(4))) float   f32x4;
typedef __attribute__((ext_vector_type(4))) unsigned short ushort4_;

__device__ __forceinline__ float bf2f(unsigned short u){
    unsigned int x = ((unsigned int)u) << 16;
    return __builtin_bit_cast(float, x);
}
__device__ __forceinline__ unsigned short f2bf(float f){
    __hip_bfloat16 h = __float2bfloat16(f);
    return __builtin_bit_cast(unsigned short, h);
}

__device__ __forceinline__ void gload16(const void* g, void* l) {
    __builtin_amdgcn_global_load_lds((const __attribute__((address_space(1))) void*)g,
                                     (__attribute__((address_space(3))) void*)l, 16, 0, 0);
}

// ---------------- bf16 MFMA GEMM, dbuf 2-phase pipeline, XCD-chunked swizzle ----
// C[M_PAD x N] = A[M_PAD x K] * BT[N x K]^T  (both bf16, row-major, K-pad of B zeroed,
// A pad rows/cols may be garbage: pad C rows are zero-guarded, pad K cols hit zero B).
// OMODE: 0 bf16 out, 1 f32 out, 2 f32 split-K partial (no bias/relu/guard).
template<int OMODE, int BIAS, int RELU>
__global__ __launch_bounds__(256)
void gemm2(const unsigned short* __restrict__ A, int lda,
           const unsigned short* __restrict__ BT, int ldb,
           const float* __restrict__ bias,
           void* __restrict__ Cp, int ldc,
           int KT, int NT, int M_real, int NSPLIT, int slab)
{
    __shared__ short smem[16384];          // 2 x (As 4096 + Bs 4096) shorts = 32 KiB

    // bijective chunked XCD swizzle (m204)
    const int nwg = gridDim.x;
    const int q = nwg >> 3, r = nwg & 7;
    const int xcd = blockIdx.x & 7, idx = blockIdx.x >> 3;
    const int wgid = (xcd < r ? xcd * (q + 1) : r * (q + 1) + (xcd - r) * q) + idx;
    const int tot_mn = nwg / NSPLIT;
    const int s  = wgid / tot_mn;
    const int mn = wgid - s * tot_mn;
    const int bm = mn / NT, bn = mn - bm * NT;

    const int t = threadIdx.x, w = t >> 6, lane = t & 63;
    const int wr = (w >> 1) * 64, wc = (w & 1) * 64;
    const int lrow = lane & 15, lq = lane >> 4;

    const int kt_beg = s * KT, kt_end = kt_beg + KT;

    const unsigned short* Ag[2];
    const unsigned short* Bg[2];
    int lds_off[2];
    #pragma unroll
    for (int cc = 0; cc < 2; ++cc) {
        int c = cc * 256 + t;
        int row = c >> 2, slot = c & 3;
        int gk = (slot ^ ((row >> 1) & 3)) << 3;   // pre-swizzled global k (rule 21)
        Ag[cc] = A  + (size_t)(bm * 128 + row) * lda + gk;
        Bg[cc] = BT + (size_t)(bn * 128 + row) * ldb + gk;
        lds_off[cc] = cc * 2048 + w * 512 + lane * 8;
    }

    auto stage = [&](int buf, int kt) {
        const int kk = kt * 32;
        #pragma unroll
        for (int cc = 0; cc < 2; ++cc) {
            gload16(Ag[cc] + kk, smem + buf * 8192 + lds_off[cc]);
            gload16(Bg[cc] + kk, smem + buf * 8192 + 4096 + lds_off[cc]);
        }
    };

    f32x4 acc[4][4] = {};
    stage(0, kt_beg);
    __syncthreads();                       // drain vmcnt: buf0 ready
    int cur = 0;
    for (int kt = kt_beg; kt < kt_end; ++kt) {
        if (kt + 1 < kt_end) stage(cur ^ 1, kt + 1);   // prefetch overlaps MFMA below
        const short* As = smem + cur * 8192;
        const short* Bs = As + 4096;
        short8 af[4], bf_[4];
        #pragma unroll
        for (int mi = 0; mi < 4; ++mi) {
            int rr = wr + mi * 16 + lrow;
            af[mi] = *(const short8*)(&As[rr * 32 + ((lq ^ ((rr >> 1) & 3)) << 3)]);
        }
        #pragma unroll
        for (int ni = 0; ni < 4; ++ni) {
            int rr = wc + ni * 16 + lrow;
            bf_[ni] = *(const short8*)(&Bs[rr * 32 + ((lq ^ ((rr >> 1) & 3)) << 3)]);
        }
        #pragma unroll
        for (int mi = 0; mi < 4; ++mi)
            #pragma unroll
            for (int ni = 0; ni < 4; ++ni)
                acc[mi][ni] = __builtin_amdgcn_mfma_f32_16x16x32_bf16(af[mi], bf_[ni], acc[mi][ni], 0, 0, 0);
        __syncthreads();                   // one barrier/K-step (drains vm+lgkm)
        cur ^= 1;
    }

    // epilogue: C/D layout col=lane&15, row=(lane>>4)*4+q (m89 verified)
    float* Cf = (float*)Cp + (size_t)s * slab;
    #pragma unroll
    for (int mi = 0; mi < 4; ++mi) {
        #pragma unroll
        for (int ni = 0; ni < 4; ++ni) {
            int gcol = bn * 128 + wc + ni * 16 + lrow;
            #pragma unroll
            for (int qq = 0; qq < 4; ++qq) {
                int grow = bm * 128 + wr + mi * 16 + lq * 4 + qq;
                float val = acc[mi][ni][qq];
                if constexpr (OMODE == 2) {
                    Cf[(size_t)grow * ldc + gcol] = val;
                } else {
                    if constexpr (BIAS) val += bias[gcol];
                    if constexpr (RELU) val = fmaxf(val, 0.f);
                    if (grow >= M_real) val = 0.f;
                    if constexpr (OMODE == 0)
                        ((unsigned short*)Cp)[(size_t)grow * ldc + gcol] = f2bf(val);
                    else
                        ((float*)Cp)[(size_t)grow * ldc + gcol] = val;
                }
            }
        }
    }
}

// ---------------- fp32 -> bf16, one block per row (k<2000 only; pads untouched) ----
__global__ void convert0_k(const float* __restrict__ x, unsigned short* __restrict__ out)
{
    int row = blockIdx.x, t = threadIdx.x;
    if (t >= 250) return;
    int kc = t * 8;
    f32x4 a0 = *(const f32x4*)(x + (size_t)row * NUM_GENE + kc);
    f32x4 a1 = *(const f32x4*)(x + (size_t)row * NUM_GENE + kc + 4);
    short8 v;
    #pragma unroll
    for (int i = 0; i < 4; ++i) { v[i] = (short)f2bf(a0[i]); v[4 + i] = (short)f2bf(a1[i]); }
    *(short8*)(out + (size_t)row * KPAD_G + kc) = v;
}

// x_aug = x + noise/||noise||  (row-norm fused), bf16 out
__global__ void convert_aug_k(const float* __restrict__ x, const float* __restrict__ noise,
                              unsigned short* __restrict__ out)
{
    __shared__ float sred[4];
    __shared__ float srn;
    int row = blockIdx.x, t = threadIdx.x;
    int kc = t * 8;
    f32x4 n0 = {}, n1 = {};
    float ss = 0.f;
    if (t < 250) {
        n0 = *(const f32x4*)(noise + (size_t)row * NUM_GENE + kc);
        n1 = *(const f32x4*)(noise + (size_t)row * NUM_GENE + kc + 4);
        ss = n0.x*n0.x + n0.y*n0.y + n0.z*n0.z + n0.w*n0.w
           + n1.x*n1.x + n1.y*n1.y + n1.z*n1.z + n1.w*n1.w;
    }
    for (int off = 32; off; off >>= 1) ss += __shfl_down(ss, off);
    if ((t & 63) == 0) sred[t >> 6] = ss;
    __syncthreads();
    if (t == 0) srn = 1.f / fmaxf(sqrtf(sred[0] + sred[1] + sred[2] + sred[3]), 1e-12f);
    __syncthreads();
    if (t >= 250) return;
    float rn = srn;
    f32x4 a0 = *(const f32x4*)(x + (size_t)row * NUM_GENE + kc);
    f32x4 a1 = *(const f32x4*)(x + (size_t)row * NUM_GENE + kc + 4);
    a0 = a0 + n0 * rn;
    a1 = a1 + n1 * rn;
    short8 v;
    #pragma unroll
    for (int i = 0; i < 4; ++i) { v[i] = (short)f2bf(a0[i]); v[4 + i] = (short)f2bf(a1[i]); }
    *(short8*)(out + (size_t)row * KPAD_G + kc) = v;
}

// ---------------- split-K reduce + bias + relu -> bf16 ----------------
__global__ void splitred_k(const float* __restrict__ part, const float* __restrict__ bm1,
                           unsigned short* __restrict__ out)
{
    int gid = blockIdx.x * 256 + threadIdx.x;     // 4 elems each
    int row = gid >> 5, c4 = (gid & 31) * 4;
    if (row >= N_NODESC) return;
    size_t o = (size_t)row * 128 + c4;
    const size_t slab = (size_t)M_PAD * 128;
    f32x4 v = *(const f32x4*)(part + o) + *(const f32x4*)(part + slab + o)
            + *(const f32x4*)(part + 2 * slab + o) + *(const f32x4*)(part + 3 * slab + o);
    f32x4 b = *(const f32x4*)(bm1 + c4);
    ushort4_ u;
    u.x = f2bf(fmaxf(v.x + b.x, 0.f)); u.y = f2bf(fmaxf(v.y + b.y, 0.f));
    u.z = f2bf(fmaxf(v.z + b.z, 0.f)); u.w = f2bf(fmaxf(v.w + b.w, 0.f));
    *(ushort4_*)(out + o) = u;
}

// ---------------- transpose + fp32->bf16 (+K pad zeroed) ----------------
__global__ void transpose_bf_k(const float* __restrict__ in, unsigned short* __restrict__ out,
                               int R, int C, int Kpad)
{
    __shared__ float tile[32][33];
    int tx = threadIdx.x & 31, ty = threadIdx.x >> 5;
    int c0 = blockIdx.x * 32, r0 = blockIdx.y * 32;
    #pragma unroll
    for (int i = 0; i < 4; ++i) {
        int r = r0 + ty + i * 8, c = c0 + tx;
        tile[ty + i * 8][tx] = (r < R && c < C) ? in[(size_t)r * C + c] : 0.f;
    }
    __syncthreads();
    #pragma unroll
    for (int i = 0; i < 4; ++i) {
        int c = c0 + ty + i * 8;
        int r = r0 + tx;
        if (c < C && r < Kpad) out[(size_t)c * Kpad + r] = f2bf(tile[tx][ty + i * 8]);
    }
}

// ---------------- CSR build by dst ----------------
__global__ void hist_k(const int* __restrict__ ei, int* __restrict__ cnt)
{
    int e = blockIdx.x * 256 + threadIdx.x;
    if (e >= E_TOT) return;
    int d = (e < N_EDGESC) ? ei[N_EDGESC + e] : (e - N_EDGESC);
    atomicAdd(&cnt[d], 1);
}

__global__ void scan_k(const int* __restrict__ cnt, int* __restrict__ row_ptr, int* __restrict__ cursor)
{
    __shared__ int buf[1024];
    __shared__ int carry;
    int t = threadIdx.x;
    if (t == 0) carry = 0;
    __syncthreads();
    for (int ch = 0; ch < 10; ++ch) {
        int i = ch * 1024 + t;
        int v = (i < N_NODESC) ? cnt[i] : 0;
        buf[t] = v; __syncthreads();
        for (int off = 1; off < 1024; off <<= 1) {
            int tmp = (t >= off) ? buf[t - off] : 0;
            __syncthreads();
            buf[t] += tmp;
            __syncthreads();
        }
        int excl = buf[t] - v;
        int tot = buf[1023];
        if (i < N_NODESC) { row_ptr[i] = carry + excl; cursor[i] = carry + excl; }
        __syncthreads();
        if (t == 0) carry += tot;
        __syncthreads();
    }
    if (t == 0) row_ptr[N_NODESC] = carry;
}

__global__ void scatter_k(const int* __restrict__ ei, int* __restrict__ cursor, int* __restrict__ col_src)
{
    int e = blockIdx.x * 256 + threadIdx.x;
    if (e >= E_TOT) return;
    int s, d;
    if (e < N_EDGESC) { s = ei[e]; d = ei[N_EDGESC + e]; } else { s = d = e - N_EDGESC; }
    int pos = atomicAdd(&cursor[d], 1);
    col_src[pos] = s;
}

// ---------------- attention scores, vectorized: 320 thr = 2 nodes ----------------
__global__ void escores2_k(const unsigned short* __restrict__ h,
                           const float* __restrict__ a_src, const float* __restrict__ a_dst,
                           float* __restrict__ e_s, float* __restrict__ e_d)
{
    int t = threadIdx.x;
    int half = (t >= 160);
    int tl = t - half * 160;
    int node = blockIdx.x * 2 + half;
    int hh = tl >> 4, c = tl & 15;
    int off = hh * 128 + c * 8;
    short8 v = *(const short8*)(h + (size_t)node * F1 + off);
    float ps = 0.f, pd = 0.f;
    #pragma unroll
    for (int j = 0; j < 8; ++j) {
        float f = bf2f((unsigned short)v[j]);
        ps += f * a_src[off + j];
        pd += f * a_dst[off + j];
    }
    #pragma unroll
    for (int m = 1; m < 16; m <<= 1) {
        ps += __shfl_xor(ps, m, 16);
        pd += __shfl_xor(pd, m, 16);
    }
    if (c == 0) { e_s[node * HEADS + hh] = ps; e_d[node * HEADS + hh] = pd; }
}

// ---------------- per-edge softmax weights ----------------
__global__ void edge_w_k(const int* __restrict__ row_ptr, const int* __restrict__ col_src,
                         const float* __restrict__ e_s, const float* __restrict__ e_d,
                         float* __restrict__ w_all)
{
    int gid = blockIdx.x * 256 + threadIdx.x;
    if (gid >= N_NODESC * HEADS) return;
    int n = gid / HEADS, hh = gid - n * HEADS;
    int beg = row_ptr[n], end = row_ptr[n + 1];
    float ed = e_d[n * HEADS + hh];
    float m = -1e30f;
    for (int e = beg; e < end; ++e) {
        float a = e_s[col_src[e] * HEADS + hh] + ed;
        a = a >= 0.f ? a : 0.2f * a;
        m = fmaxf(m, a);
    }
    float s = 0.f;
    for (int e = beg; e < end; ++e) {
        float a = e_s[col_src[e] * HEADS + hh] + ed;
        a = a >= 0.f ? a : 0.2f * a;
        s += __expf(a - m);
    }
    float inv = 1.f / s;
    for (int e = beg; e < end; ++e) {
        float a = e_s[col_src[e] * HEADS + hh] + ed;
        a = a >= 0.f ? a : 0.2f * a;
        w_all[(size_t)e * HEADS + hh] = __expf(a - m) * inv;
    }
}

// ---------------- layer1 aggregate (concat) -> bf16; 320 thr = 2 nodes, 16B gathers ----
__global__ void agg1_k(const int* __restrict__ row_ptr, const int* __restrict__ col_src,
                       const float* __restrict__ w_all,
                       const unsigned short* __restrict__ h, const float* __restrict__ b1,
                       unsigned short* __restrict__ out)
{
    int t = threadIdx.x;
    int half = (t >= 160);
    int tl = t - half * 160;
    int node = blockIdx.x * 2 + half;
    int f0 = tl * 8, hh = tl >> 4;
    int beg = row_ptr[node], end = row_ptr[node + 1];
    float acc[8] = {};
    for (int e = beg; e < end; ++e) {
        int s = col_src[e];
        float w = w_all[(size_t)e * HEADS + hh];
        short8 r = *(const short8*)(h + (size_t)s * F1 + f0);
        #pragma unroll
        for (int j = 0; j < 8; ++j) acc[j] += w * bf2f((unsigned short)r[j]);
    }
    short8 o;
    #pragma unroll
    for (int j = 0; j < 8; ++j) o[j] = (short)f2bf(fmaxf(acc[j] + b1[f0 + j], 0.f));
    *(short8*)(out + (size_t)node * F1 + f0) = o;
}

// ---------------- layer2 aggregate (head mean) -> f32; 320 thr = 2 nodes ----------------
__global__ void agg2_k(const int* __restrict__ row_ptr, const int* __restrict__ col_src,
                       const float* __restrict__ w_all,
                       const unsigned short* __restrict__ h, const float* __restrict__ b2,
                       float* __restrict__ out)
{
    __shared__ float red[2][160][8];
    int t = threadIdx.x;
    int half = (t >= 160);
    int tl = t - half * 160;
    int node = blockIdx.x * 2 + half;
    int f0 = tl * 8, hh = tl >> 4;
    int beg = row_ptr[node], end = row_ptr[node + 1];
    float acc[8] = {};
    for (int e = beg; e < end; ++e) {
        int s = col_src[e];
        float w = w_all[(size_t)e * HEADS + hh];
        short8 r = *(const short8*)(h + (size_t)s * F1 + f0);
        #pragma unroll
        for (int j = 0; j < 8; ++j) acc[j] += w * bf2f((unsigned short)r[j]);
    }
    #pragma unroll
    for (int j = 0; j < 8; ++j) red[half][tl][j] = acc[j];
    __syncthreads();
    // threads 0..127 -> node of half0, threads 160..287 -> node of half1
    if (tl < 128) {
        int c = tl >> 3, j = tl & 7;
        float s = 0.f;
        #pragma unroll
        for (int hq = 0; hq < HEADS; ++hq) s += red[half][hq * 16 + c][j];
        out[(size_t)node * LATENTC + tl] = fmaxf(s * 0.1f + b2[tl], 0.f);
    }
}

// ---------------- column sums for pooling (real rows only) ----------------
__global__ void colsum_k(const float* __restrict__ g0, const float* __restrict__ g1,
                         const float* __restrict__ g2, float* __restrict__ gsum)
{
    int v = blockIdx.x / 40, b = blockIdx.x % 40;
    const float* src = (v == 0) ? g0 : (v == 1) ? g1 : g2;
    int t = threadIdx.x, col = t & 127, ro = t >> 7;
    int rend = min((b + 1) * 250, N_NODESC);
    float acc = 0.f;
    for (int r = b * 250 + ro; r < rend; r += 2) acc += src[(size_t)r * 128 + col];
    __shared__ float part[256];
    part[t] = acc; __syncthreads();
    if (t < 128) atomicAdd(&gsum[v * 128 + col], part[t] + part[t + 128]);
}

// ---------------- contrastive loss scalar ----------------
__global__ void loss_k(const float* __restrict__ gsum, float* __restrict__ out)
{
    int t = threadIdx.x;   // 128
    float g0 = gsum[t] * 1e-4f, g1 = gsum[128 + t] * 1e-4f, g2 = gsum[256 + t] * 1e-4f;
    float d01 = g0 * g1, d02 = g0 * g2, d12 = g1 * g2;
    for (int off = 32; off; off >>= 1) {
        d01 += __shfl_down(d01, off); d02 += __shfl_down(d02, off); d12 += __shfl_down(d12, off);
    }
    __shared__ float s[3][2];
    if ((t & 63) == 0) { int w = t >> 6; s[0][w] = d01; s[1][w] = d02; s[2][w] = d12; }
    __syncthreads();
    if (t == 0) {
        float a01 = (s[0][0] + s[0][1]) * 5.f;
        float a02 = (s[1][0] + s[1][1]) * 5.f;
        float a12 = (s[2][0] + s[2][1]) * 5.f;
        float m = fmaxf(a01, fmaxf(a02, a12));
        float se = expf(a01 - m) + expf(a02 - m) + expf(a12 - m);
        *out = -((a01 - m) - logf(se)) / 2.302585092994046f;
    }
}

// ---------------- projection heads, all 3 matrices in one launch ----------------
__global__ void proj_k(const float* __restrict__ g0, const float* __restrict__ g1,
                       const float* __restrict__ g2,
                       const float* __restrict__ Wf, const float* __restrict__ bfv,
                       const float* __restrict__ Wc, const float* __restrict__ bc,
                       float* __restrict__ out)
{
    __shared__ float rowb[4][128];
    int m = blockIdx.y;
    const float* gx = (m == 0) ? g0 : (m == 1) ? g1 : g2;
    float* out_node = out + (size_t)m * 640000;
    float* out_c = (m == 0) ? out + 1920001 : (m == 1) ? out + 2070001 : nullptr;
    int wid = threadIdx.x >> 6, l = threadIdx.x & 63;
    int n = blockIdx.x * 4 + wid;
    if (n >= N_NODESC) return;
    rowb[wid][l]      = gx[(size_t)n * 128 + l];
    rowb[wid][l + 64] = gx[(size_t)n * 128 + 64 + l];
    float acc = bfv[l];
    #pragma unroll 8
    for (int k = 0; k < 128; ++k) acc += rowb[wid][k] * Wf[k * 64 + l];
    out_node[(size_t)n * 64 + l] = acc;
    if (out_c != nullptr && l < CLUST) {
        float a2 = bc[l];
        #pragma unroll 8
        for (int k = 0; k < 128; ++k) a2 += rowb[wid][k] * Wc[k * CLUST + l];
        out_c[(size_t)l * N_NODESC + n] = a2;
    }
}

// ---------------- host ----------------
extern "C" void kernel_launch(void* const* d_in, const int* in_sizes, int n_in,
                              void* d_out, int out_size, void* d_ws, size_t ws_size,
                              hipStream_t stream)
{
    const float* x     = (const float*)d_in[0];
    const int*   ei    = (const int*)  d_in[1];
    const float* noise = (const float*)d_in[2];
    const float* W1    = (const float*)d_in[3];
    const float* a1s   = (const float*)d_in[4];
    const float* a1d   = (const float*)d_in[5];
    const float* b1    = (const float*)d_in[6];
    const float* W2    = (const float*)d_in[7];
    const float* a2s   = (const float*)d_in[8];
    const float* a2d   = (const float*)d_in[9];
    const float* b2    = (const float*)d_in[10];
    const float* Wm1   = (const float*)d_in[11];
    const float* bm1   = (const float*)d_in[12];
    const float* Wm2   = (const float*)d_in[13];
    const float* bm2   = (const float*)d_in[14];
    const float* Wf    = (const float*)d_in[15];
    const float* bfv   = (const float*)d_in[16];
    const float* Wc    = (const float*)d_in[17];
    const float* bc    = (const float*)d_in[18];
    float* out = (float*)d_out;

    size_t off = 0;
    auto alloc = [&](size_t bytes) { size_t o = off; off = (off + bytes + 255) & ~(size_t)255; return o; };
    char* ws = (char*)d_ws;
    unsigned short* w1t   = (unsigned short*)(ws + alloc((size_t)F1 * KPAD_G * 2));
    unsigned short* w2t   = (unsigned short*)(ws + alloc((size_t)F1 * F1 * 2));
    unsigned short* wm1t  = (unsigned short*)(ws + alloc((size_t)128 * KPAD_G * 2));
    unsigned short* wm2t  = (unsigned short*)(ws + alloc((size_t)128 * 128 * 2));
    unsigned short* h_raw = (unsigned short*)(ws + alloc((size_t)M_PAD * F1 * 2));
    unsigned short* h1x   = (unsigned short*)(ws + alloc((size_t)M_PAD * F1 * 2));
    unsigned short* t_bf  = (unsigned short*)(ws + alloc((size_t)M_PAD * 128 * 2));
    unsigned short* xbuf  = (unsigned short*)(ws + alloc((size_t)M_PAD * KPAD_G * 2));
    float* gxpart = (float*)(ws + alloc((size_t)4 * M_PAD * 128 * 4));
    float* es     = (float*)(ws + alloc((size_t)N_NODESC * HEADS * 4));
    float* ed     = (float*)(ws + alloc((size_t)N_NODESC * HEADS * 4));
    float* w_all  = (float*)(ws + alloc((size_t)E_TOT * HEADS * 4));
    int*   cnt    = (int*)  (ws + alloc((size_t)N_NODESC * 4));
    int*   rowp   = (int*)  (ws + alloc((size_t)(N_NODESC + 16) * 4));
    int*   cursor = (int*)  (ws + alloc((size_t)N_NODESC * 4));
    int*   colsrc = (int*)  (ws + alloc((size_t)E_TOT * 4));
    float* gx     = (float*)(ws + alloc((size_t)M_PAD * 128 * 4));
    float* gx1    = (float*)(ws + alloc((size_t)M_PAD * 128 * 4));
    float* gx2    = (float*)(ws + alloc((size_t)M_PAD * 128 * 4));
    float* gsum   = (float*)(ws + alloc((size_t)384 * 4));
    (void)ws_size; (void)in_sizes; (void)n_in; (void)out_size;

    hipMemsetAsync(cnt, 0, (size_t)N_NODESC * 4, stream);
    hipMemsetAsync(gsum, 0, 384 * 4, stream);

    convert0_k<<<N_NODESC, 256, 0, stream>>>(x, xbuf);

    transpose_bf_k<<<dim3(40, 64), 256, 0, stream>>>(W1,  w1t,  NUM_GENE, F1,  KPAD_G);
    transpose_bf_k<<<dim3(40, 40), 256, 0, stream>>>(W2,  w2t,  F1,       F1,  F1);
    transpose_bf_k<<<dim3(4, 64),  256, 0, stream>>>(Wm1, wm1t, NUM_GENE, 128, KPAD_G);
    transpose_bf_k<<<dim3(4, 4),   256, 0, stream>>>(Wm2, wm2t, 128,      128, 128);

    hist_k   <<<(E_TOT + 255) / 256, 256, 0, stream>>>(ei, cnt);
    scan_k   <<<1, 1024, 0, stream>>>(cnt, rowp, cursor);
    scatter_k<<<(E_TOT + 255) / 256, 256, 0, stream>>>(ei, cursor, colsrc);

    // MLP branch: split-K x4 (79 -> 316 blocks), then reduce, then 128x128 GEMM
    gemm2<2,0,0><<<RT_TILES * 4, 256, 0, stream>>>(xbuf, KPAD_G, wm1t, KPAD_G,
        nullptr, gxpart, 128, 16, 1, N_NODESC, 4, M_PAD * 128);
    splitred_k<<<1250, 256, 0, stream>>>(gxpart, bm1, t_bf);
    gemm2<1,1,0><<<RT_TILES, 256, 0, stream>>>(t_bf, 128, wm2t, 128,
        bm2, gx2, 128, 4, 1, N_NODESC, 1, 0);

    for (int p = 0; p < 2; ++p) {
        if (p == 1)
            convert_aug_k<<<N_NODESC, 256, 0, stream>>>(x, noise, xbuf);
        gemm2<0,0,0><<<RT_TILES * 10, 256, 0, stream>>>(xbuf, KPAD_G, w1t, KPAD_G,
            nullptr, h_raw, F1, 64, 10, N_NODESC, 1, 0);
        escores2_k<<<N_NODESC / 2, 320, 0, stream>>>(h_raw, a1s, a1d, es, ed);
        edge_w_k <<<(N_NODESC * HEADS + 255) / 256, 256, 0, stream>>>(rowp, colsrc, es, ed, w_all);
        agg1_k   <<<N_NODESC / 2, 320, 0, stream>>>(rowp, colsrc, w_all, h_raw, b1, h1x);
        gemm2<0,0,0><<<RT_TILES * 10, 256, 0, stream>>>(h1x, F1, w2t, F1,
            nullptr, h_raw, F1, 40, 10, N_NODESC, 1, 0);
        escores2_k<<<N_NODESC / 2, 320, 0, stream>>>(h_raw, a2s, a2d, es, ed);
        edge_w_k <<<(N_NODESC * HEADS + 255) / 256, 256, 0, stream>>>(rowp, colsrc, es, ed, w_all);
        agg2_k   <<<N_NODESC / 2, 320, 0, stream>>>(rowp, colsrc, w_all, h_raw, b2, p == 0 ? gx : gx1);
    }

    colsum_k<<<120, 256, 0, stream>>>(gx, gx1, gx2, gsum);
    loss_k  <<<1, 128, 0, stream>>>(gsum, out + 1920000);

    proj_k<<<dim3(2500, 3), 256, 0, stream>>>(gx, gx1, gx2, Wf, bfv, Wc, bc, out);
}

// Round 4
// 799.057 us; speedup vs baseline: 1.7615x; 1.1866x over previous
//
#include <hip/hip_runtime.h>
#include <hip/hip_bf16.h>

// ---------------- problem constants ----------------
#define N_NODESC 10000
#define M_PAD    10112          // 79 * 128
#define RT_TILES 79
#define MT2      158            // combined 2-pass row tiles
#define NUM_GENE 2000
#define KPAD_G   2048
#define N_EDGESC 160000
#define E_TOT    170000         // + self loops
#define HEADS    10
#define F1       1280           // HEADS*128
#define LATENTC  128
#define LOWERC   64
#define CLUST    15

typedef __attribute__((ext_vector_type(8))) short   short8;
typedef __attribute__((ext_vector_type(4))) float   f32x4;
typedef __attribute__((ext_vector_type(4))) unsigned short ushort4_;

__device__ __forceinline__ float bf2f(unsigned short u){
    unsigned int x = ((unsigned int)u) << 16;
    return __builtin_bit_cast(float, x);
}
__device__ __forceinline__ unsigned short f2bf(float f){
    __hip_bfloat16 h = __float2bfloat16(f);
    return __builtin_bit_cast(unsigned short, h);
}
__device__ __forceinline__ void gload16(const void* g, void* l) {
    __builtin_amdgcn_global_load_lds((const __attribute__((address_space(1))) void*)g,
                                     (__attribute__((address_space(3))) void*)l, 16, 0, 0);
}

// ---------------- bf16 MFMA GEMM, dbuf 2-phase, XCD-chunked swizzle ----------------
// C[rows x N] = A * BT^T.  Row guard: rows with (grow mod M_PAD-slab) >= M_real -> 0.
// OMODE: 0 bf16 out, 1 f32 out, 2 f32 split-K partial (no guard/bias/relu).
template<int OMODE, int BIAS, int RELU>
__global__ __launch_bounds__(256)
void gemm2(const unsigned short* __restrict__ A, int lda,
           const unsigned short* __restrict__ BT, int ldb,
           const float* __restrict__ bias,
           void* __restrict__ Cp, int ldc,
           int KT, int NT, int M_real, int NSPLIT, int slab)
{
    __shared__ short smem[16384];          // 2 x (As 4096 + Bs 4096) = 32 KiB

    const int nwg = gridDim.x;
    const int q = nwg >> 3, r = nwg & 7;
    const int xcd = blockIdx.x & 7, idx = blockIdx.x >> 3;
    const int wgid = (xcd < r ? xcd * (q + 1) : r * (q + 1) + (xcd - r) * q) + idx;
    const int tot_mn = nwg / NSPLIT;
    const int s  = wgid / tot_mn;
    const int mn = wgid - s * tot_mn;
    const int bm = mn / NT, bn = mn - bm * NT;

    const int t = threadIdx.x, w = t >> 6, lane = t & 63;
    const int wr = (w >> 1) * 64, wc = (w & 1) * 64;
    const int lrow = lane & 15, lq = lane >> 4;

    const int kt_beg = s * KT, kt_end = kt_beg + KT;

    const unsigned short* Ag[2];
    const unsigned short* Bg[2];
    int lds_off[2];
    #pragma unroll
    for (int cc = 0; cc < 2; ++cc) {
        int c = cc * 256 + t;
        int row = c >> 2, slot = c & 3;
        int gk = (slot ^ ((row >> 1) & 3)) << 3;   // pre-swizzled global k (rule 21)
        Ag[cc] = A  + (size_t)(bm * 128 + row) * lda + gk;
        Bg[cc] = BT + (size_t)(bn * 128 + row) * ldb + gk;
        lds_off[cc] = cc * 2048 + w * 512 + lane * 8;
    }

    auto stage = [&](int buf, int kt) {
        const int kk = kt * 32;
        #pragma unroll
        for (int cc = 0; cc < 2; ++cc) {
            gload16(Ag[cc] + kk, smem + buf * 8192 + lds_off[cc]);
            gload16(Bg[cc] + kk, smem + buf * 8192 + 4096 + lds_off[cc]);
        }
    };

    f32x4 acc[4][4] = {};
    stage(0, kt_beg);
    __syncthreads();
    int cur = 0;
    for (int kt = kt_beg; kt < kt_end; ++kt) {
        if (kt + 1 < kt_end) stage(cur ^ 1, kt + 1);
        const short* As = smem + cur * 8192;
        const short* Bs = As + 4096;
        short8 af[4], bf_[4];
        #pragma unroll
        for (int mi = 0; mi < 4; ++mi) {
            int rr = wr + mi * 16 + lrow;
            af[mi] = *(const short8*)(&As[rr * 32 + ((lq ^ ((rr >> 1) & 3)) << 3)]);
        }
        #pragma unroll
        for (int ni = 0; ni < 4; ++ni) {
            int rr = wc + ni * 16 + lrow;
            bf_[ni] = *(const short8*)(&Bs[rr * 32 + ((lq ^ ((rr >> 1) & 3)) << 3)]);
        }
        #pragma unroll
        for (int mi = 0; mi < 4; ++mi)
            #pragma unroll
            for (int ni = 0; ni < 4; ++ni)
                acc[mi][ni] = __builtin_amdgcn_mfma_f32_16x16x32_bf16(af[mi], bf_[ni], acc[mi][ni], 0, 0, 0);
        __syncthreads();
        cur ^= 1;
    }

    float* Cf = (float*)Cp + (size_t)s * slab;
    #pragma unroll
    for (int mi = 0; mi < 4; ++mi) {
        #pragma unroll
        for (int ni = 0; ni < 4; ++ni) {
            int gcol = bn * 128 + wc + ni * 16 + lrow;
            #pragma unroll
            for (int qq = 0; qq < 4; ++qq) {
                int grow = bm * 128 + wr + mi * 16 + lq * 4 + qq;
                float val = acc[mi][ni][qq];
                if constexpr (OMODE == 2) {
                    Cf[(size_t)grow * ldc + gcol] = val;
                } else {
                    if constexpr (BIAS) val += bias[gcol];
                    if constexpr (RELU) val = fmaxf(val, 0.f);
                    int rr = grow >= M_PAD ? grow - M_PAD : grow;   // 2-pass slab guard
                    if (rr >= M_real) val = 0.f;
                    if constexpr (OMODE == 0)
                        ((unsigned short*)Cp)[(size_t)grow * ldc + gcol] = f2bf(val);
                    else
                        ((float*)Cp)[(size_t)grow * ldc + gcol] = val;
                }
            }
        }
    }
}

// ---------------- fp32 -> bf16 (slab 0) ----------------
__global__ void convert0_k(const float* __restrict__ x, unsigned short* __restrict__ out)
{
    int row = blockIdx.x, t = threadIdx.x;
    if (t >= 250) return;
    int kc = t * 8;
    f32x4 a0 = *(const f32x4*)(x + (size_t)row * NUM_GENE + kc);
    f32x4 a1 = *(const f32x4*)(x + (size_t)row * NUM_GENE + kc + 4);
    short8 v;
    #pragma unroll
    for (int i = 0; i < 4; ++i) { v[i] = (short)f2bf(a0[i]); v[4 + i] = (short)f2bf(a1[i]); }
    *(short8*)(out + (size_t)row * KPAD_G + kc) = v;
}

// x_aug = x + noise/||noise|| -> bf16 (slab 1)
__global__ void convert_aug_k(const float* __restrict__ x, const float* __restrict__ noise,
                              unsigned short* __restrict__ out)
{
    __shared__ float sred[4];
    __shared__ float srn;
    int row = blockIdx.x, t = threadIdx.x;
    int kc = t * 8;
    f32x4 n0 = {}, n1 = {};
    float ss = 0.f;
    if (t < 250) {
        n0 = *(const f32x4*)(noise + (size_t)row * NUM_GENE + kc);
        n1 = *(const f32x4*)(noise + (size_t)row * NUM_GENE + kc + 4);
        ss = n0.x*n0.x + n0.y*n0.y + n0.z*n0.z + n0.w*n0.w
           + n1.x*n1.x + n1.y*n1.y + n1.z*n1.z + n1.w*n1.w;
    }
    for (int off = 32; off; off >>= 1) ss += __shfl_down(ss, off);
    if ((t & 63) == 0) sred[t >> 6] = ss;
    __syncthreads();
    if (t == 0) srn = 1.f / fmaxf(sqrtf(sred[0] + sred[1] + sred[2] + sred[3]), 1e-12f);
    __syncthreads();
    if (t >= 250) return;
    float rn = srn;
    f32x4 a0 = *(const f32x4*)(x + (size_t)row * NUM_GENE + kc);
    f32x4 a1 = *(const f32x4*)(x + (size_t)row * NUM_GENE + kc + 4);
    a0 = a0 + n0 * rn;
    a1 = a1 + n1 * rn;
    short8 v;
    #pragma unroll
    for (int i = 0; i < 4; ++i) { v[i] = (short)f2bf(a0[i]); v[4 + i] = (short)f2bf(a1[i]); }
    *(short8*)(out + (size_t)(M_PAD + row) * KPAD_G + kc) = v;
}

// ---------------- split-K reduce + bias + relu -> bf16 ----------------
__global__ void splitred_k(const float* __restrict__ part, const float* __restrict__ bm1,
                           unsigned short* __restrict__ out)
{
    int gid = blockIdx.x * 256 + threadIdx.x;
    int row = gid >> 5, c4 = (gid & 31) * 4;
    if (row >= N_NODESC) return;
    size_t o = (size_t)row * 128 + c4;
    const size_t slab = (size_t)M_PAD * 128;
    f32x4 v = *(const f32x4*)(part + o) + *(const f32x4*)(part + slab + o)
            + *(const f32x4*)(part + 2 * slab + o) + *(const f32x4*)(part + 3 * slab + o);
    f32x4 b = *(const f32x4*)(bm1 + c4);
    ushort4_ u;
    u.x = f2bf(fmaxf(v.x + b.x, 0.f)); u.y = f2bf(fmaxf(v.y + b.y, 0.f));
    u.z = f2bf(fmaxf(v.z + b.z, 0.f)); u.w = f2bf(fmaxf(v.w + b.w, 0.f));
    *(ushort4_*)(out + o) = u;
}

// ---------------- transpose + fp32->bf16 (+K pad zeroed) ----------------
__global__ void transpose_bf_k(const float* __restrict__ in, unsigned short* __restrict__ out,
                               int R, int C, int Kpad)
{
    __shared__ float tile[32][33];
    int tx = threadIdx.x & 31, ty = threadIdx.x >> 5;
    int c0 = blockIdx.x * 32, r0 = blockIdx.y * 32;
    #pragma unroll
    for (int i = 0; i < 4; ++i) {
        int r = r0 + ty + i * 8, c = c0 + tx;
        tile[ty + i * 8][tx] = (r < R && c < C) ? in[(size_t)r * C + c] : 0.f;
    }
    __syncthreads();
    #pragma unroll
    for (int i = 0; i < 4; ++i) {
        int c = c0 + ty + i * 8;
        int r = r0 + tx;
        if (c < C && r < Kpad) out[(size_t)c * Kpad + r] = f2bf(tile[tx][ty + i * 8]);
    }
}

// ---------------- CSR build by dst ----------------
__global__ void hist_k(const int* __restrict__ ei, int* __restrict__ cnt)
{
    int e = blockIdx.x * 256 + threadIdx.x;
    if (e >= E_TOT) return;
    int d = (e < N_EDGESC) ? ei[N_EDGESC + e] : (e - N_EDGESC);
    atomicAdd(&cnt[d], 1);
}

__global__ void scan_k(const int* __restrict__ cnt, int* __restrict__ rowp, int* __restrict__ cursor)
{
    __shared__ int buf[1024];
    int t = threadIdx.x;
    int loc[10];
    int s = 0, base = t * 10;
    #pragma unroll
    for (int i = 0; i < 10; ++i) {
        int idx = base + i;
        int v = (idx < N_NODESC) ? cnt[idx] : 0;
        loc[i] = v; s += v;
    }
    buf[t] = s; __syncthreads();
    for (int off = 1; off < 1024; off <<= 1) {
        int tmp = (t >= off) ? buf[t - off] : 0;
        __syncthreads();
        buf[t] += tmp;
        __syncthreads();
    }
    int run = buf[t] - s;   // exclusive prefix
    #pragma unroll
    for (int i = 0; i < 10; ++i) {
        int idx = base + i;
        if (idx < N_NODESC) { rowp[idx] = run; cursor[idx] = run; run += loc[i]; }
    }
    if (t == 1023) rowp[N_NODESC] = buf[1023];
}

__global__ void scatter_k(const int* __restrict__ ei, int* __restrict__ cursor,
                          int* __restrict__ col_src, int* __restrict__ dst_of)
{
    int e = blockIdx.x * 256 + threadIdx.x;
    if (e >= E_TOT) return;
    int s, d;
    if (e < N_EDGESC) { s = ei[e]; d = ei[N_EDGESC + e]; } else { s = d = e - N_EDGESC; }
    int pos = atomicAdd(&cursor[d], 1);
    col_src[pos] = s;
    dst_of[pos] = d;
}

// ---------------- attention scores for both passes; 320 thr = 2 nodes ----------------
__global__ void escores2_k(const unsigned short* __restrict__ h,
                           const float* __restrict__ a_src, const float* __restrict__ a_dst,
                           float* __restrict__ e_s, float* __restrict__ e_d)
{
    int t = threadIdx.x;
    int half = (t >= 160);
    int tl = t - half * 160;
    int node2 = blockIdx.x * 2 + half;                  // [0, 2N)
    int p = node2 >= N_NODESC;
    int n = node2 - p * N_NODESC;
    int hh = tl >> 4, c = tl & 15;
    int off = hh * 128 + c * 8;
    short8 v = *(const short8*)(h + (size_t)(p * M_PAD + n) * F1 + off);
    float ps = 0.f, pd = 0.f;
    #pragma unroll
    for (int j = 0; j < 8; ++j) {
        float f = bf2f((unsigned short)v[j]);
        ps += f * a_src[off + j];
        pd += f * a_dst[off + j];
    }
    #pragma unroll
    for (int m = 1; m < 16; m <<= 1) {
        ps += __shfl_xor(ps, m, 16);
        pd += __shfl_xor(pd, m, 16);
    }
    if (c == 0) { e_s[node2 * HEADS + hh] = ps; e_d[node2 * HEADS + hh] = pd; }
}

// ---------------- per-edge alpha (gather-once), both passes ----------------
__global__ void alpha_k(const int* __restrict__ colsrc, const int* __restrict__ dstof,
                        const float* __restrict__ e_s, const float* __restrict__ e_d,
                        float* __restrict__ alpha)
{
    int gid = blockIdx.x * 256 + threadIdx.x;
    if (gid >= 2 * E_TOT) return;
    int p = gid >= E_TOT;
    int e = gid - p * E_TOT;
    int s = colsrc[e], d = dstof[e];
    const float* er = e_s + (size_t)(p * N_NODESC + s) * HEADS;
    const float* dr = e_d + (size_t)(p * N_NODESC + d) * HEADS;
    float* o = alpha + (size_t)gid * HEADS;
    #pragma unroll
    for (int h = 0; h < HEADS; ++h) {
        float a = er[h] + dr[h];
        o[h] = a >= 0.f ? a : 0.2f * a;
    }
}

// ---------------- per-(pass,node,head) online max/sum over linear alpha ----------------
__global__ void nodems_k(const int* __restrict__ rowp, const float* __restrict__ alpha,
                         float2* __restrict__ minv)
{
    int gid = blockIdx.x * 256 + threadIdx.x;
    if (gid >= 2 * N_NODESC * HEADS) return;
    int p = gid >= N_NODESC * HEADS;
    int rr = gid - p * N_NODESC * HEADS;
    int n = rr / HEADS, hh = rr - n * HEADS;
    int beg = rowp[n], end = rowp[n + 1];
    size_t base = (size_t)p * E_TOT;
    float m = -1e30f, ssum = 0.f;
    for (int e = beg; e < end; ++e) {
        float a = alpha[(base + e) * HEADS + hh];
        if (a > m) { ssum = ssum * __expf(m - a) + 1.f; m = a; }
        else ssum += __expf(a - m);
    }
    float2 q; q.x = m; q.y = 1.f / ssum;
    minv[gid] = q;
}

// ---------------- per-edge softmax weight, in-place on alpha ----------------
__global__ void wexp_k(const int* __restrict__ dstof, const float2* __restrict__ minv,
                       float* __restrict__ alpha)
{
    int gid = blockIdx.x * 256 + threadIdx.x;
    if (gid >= 2 * E_TOT) return;
    int p = gid >= E_TOT;
    int e = gid - p * E_TOT;
    int d = dstof[e];
    const float2* mv = minv + (size_t)(p * N_NODESC + d) * HEADS;
    float* w = alpha + (size_t)gid * HEADS;
    #pragma unroll
    for (int h = 0; h < HEADS; ++h) {
        float2 q = mv[h];
        w[h] = __expf(w[h] - q.x) * q.y;
    }
}

// ---------------- layer1 aggregate (concat) -> bf16; both passes ----------------
__global__ void agg1_k(const int* __restrict__ rowp, const int* __restrict__ colsrc,
                       const float* __restrict__ w_all,
                       const unsigned short* __restrict__ h, const float* __restrict__ b1,
                       unsigned short* __restrict__ out)
{
    int t = threadIdx.x;
    int half = (t >= 160);
    int tl = t - half * 160;
    int node2 = blockIdx.x * 2 + half;
    int p = node2 >= N_NODESC;
    int n = node2 - p * N_NODESC;
    int f0 = tl * 8, hh = tl >> 4;
    int beg = rowp[n], end = rowp[n + 1];
    const unsigned short* hb = h + (size_t)p * M_PAD * F1;
    const float* wb = w_all + (size_t)p * E_TOT * HEADS;
    float acc[8] = {};
    for (int e = beg; e < end; ++e) {
        int s = colsrc[e];
        float w = wb[(size_t)e * HEADS + hh];
        short8 r = *(const short8*)(hb + (size_t)s * F1 + f0);
        #pragma unroll
        for (int j = 0; j < 8; ++j) acc[j] += w * bf2f((unsigned short)r[j]);
    }
    short8 o;
    #pragma unroll
    for (int j = 0; j < 8; ++j) o[j] = (short)f2bf(fmaxf(acc[j] + b1[f0 + j], 0.f));
    *(short8*)(out + (size_t)(p * M_PAD + n) * F1 + f0) = o;
}

// ---------------- layer2 aggregate (head mean) -> f32; both passes ----------------
__global__ void agg2_k(const int* __restrict__ rowp, const int* __restrict__ colsrc,
                       const float* __restrict__ w_all,
                       const unsigned short* __restrict__ h, const float* __restrict__ b2,
                       float* __restrict__ out)
{
    __shared__ float red[2][160][8];
    int t = threadIdx.x;
    int half = (t >= 160);
    int tl = t - half * 160;
    int node2 = blockIdx.x * 2 + half;
    int p = node2 >= N_NODESC;
    int n = node2 - p * N_NODESC;
    int f0 = tl * 8, hh = tl >> 4;
    int beg = rowp[n], end = rowp[n + 1];
    const unsigned short* hb = h + (size_t)p * M_PAD * F1;
    const float* wb = w_all + (size_t)p * E_TOT * HEADS;
    float acc[8] = {};
    for (int e = beg; e < end; ++e) {
        int s = colsrc[e];
        float w = wb[(size_t)e * HEADS + hh];
        short8 r = *(const short8*)(hb + (size_t)s * F1 + f0);
        #pragma unroll
        for (int j = 0; j < 8; ++j) acc[j] += w * bf2f((unsigned short)r[j]);
    }
    #pragma unroll
    for (int j = 0; j < 8; ++j) red[half][tl][j] = acc[j];
    __syncthreads();
    if (tl < 128) {
        int c = tl >> 3, j = tl & 7;
        float s = 0.f;
        #pragma unroll
        for (int hq = 0; hq < HEADS; ++hq) s += red[half][hq * 16 + c][j];
        out[(size_t)(p * M_PAD + n) * LATENTC + tl] = fmaxf(s * 0.1f + b2[tl], 0.f);
    }
}

// ---------------- column sums for pooling (real rows only) ----------------
__global__ void colsum_k(const float* __restrict__ g01, const float* __restrict__ g2,
                         float* __restrict__ gsum)
{
    int v = blockIdx.x / 40, b = blockIdx.x % 40;
    const float* src = (v == 0) ? g01 : (v == 1) ? g01 + (size_t)M_PAD * 128 : g2;
    int t = threadIdx.x, col = t & 127, ro = t >> 7;
    int rend = min((b + 1) * 250, N_NODESC);
    float acc = 0.f;
    for (int r = b * 250 + ro; r < rend; r += 2) acc += src[(size_t)r * 128 + col];
    __shared__ float part[256];
    part[t] = acc; __syncthreads();
    if (t < 128) atomicAdd(&gsum[v * 128 + col], part[t] + part[t + 128]);
}

// ---------------- contrastive loss scalar ----------------
__global__ void loss_k(const float* __restrict__ gsum, float* __restrict__ out)
{
    int t = threadIdx.x;   // 128
    float g0 = gsum[t] * 1e-4f, g1 = gsum[128 + t] * 1e-4f, g2 = gsum[256 + t] * 1e-4f;
    float d01 = g0 * g1, d02 = g0 * g2, d12 = g1 * g2;
    for (int off = 32; off; off >>= 1) {
        d01 += __shfl_down(d01, off); d02 += __shfl_down(d02, off); d12 += __shfl_down(d12, off);
    }
    __shared__ float s[3][2];
    if ((t & 63) == 0) { int w = t >> 6; s[0][w] = d01; s[1][w] = d02; s[2][w] = d12; }
    __syncthreads();
    if (t == 0) {
        float a01 = (s[0][0] + s[0][1]) * 5.f;
        float a02 = (s[1][0] + s[1][1]) * 5.f;
        float a12 = (s[2][0] + s[2][1]) * 5.f;
        float m = fmaxf(a01, fmaxf(a02, a12));
        float se = expf(a01 - m) + expf(a02 - m) + expf(a12 - m);
        *out = -((a01 - m) - logf(se)) / 2.302585092994046f;
    }
}

// ---------------- projection heads ----------------
__global__ void proj_k(const float* __restrict__ g01, const float* __restrict__ g2,
                       const float* __restrict__ Wf, const float* __restrict__ bfv,
                       const float* __restrict__ Wc, const float* __restrict__ bc,
                       float* __restrict__ out)
{
    __shared__ float rowb[4][128];
    int m = blockIdx.y;
    const float* gx = (m == 0) ? g01 : (m == 1) ? g01 + (size_t)M_PAD * 128 : g2;
    float* out_node = out + (size_t)m * 640000;
    float* out_c = (m == 0) ? out + 1920001 : (m == 1) ? out + 2070001 : nullptr;
    int wid = threadIdx.x >> 6, l = threadIdx.x & 63;
    int n = blockIdx.x * 4 + wid;
    if (n >= N_NODESC) return;
    rowb[wid][l]      = gx[(size_t)n * 128 + l];
    rowb[wid][l + 64] = gx[(size_t)n * 128 + 64 + l];
    float acc = bfv[l];
    #pragma unroll 8
    for (int k = 0; k < 128; ++k) acc += rowb[wid][k] * Wf[k * 64 + l];
    out_node[(size_t)n * 64 + l] = acc;
    if (out_c != nullptr && l < CLUST) {
        float a2 = bc[l];
        #pragma unroll 8
        for (int k = 0; k < 128; ++k) a2 += rowb[wid][k] * Wc[k * CLUST + l];
        out_c[(size_t)l * N_NODESC + n] = a2;
    }
}

// ---------------- host ----------------
extern "C" void kernel_launch(void* const* d_in, const int* in_sizes, int n_in,
                              void* d_out, int out_size, void* d_ws, size_t ws_size,
                              hipStream_t stream)
{
    const float* x     = (const float*)d_in[0];
    const int*   ei    = (const int*)  d_in[1];
    const float* noise = (const float*)d_in[2];
    const float* W1    = (const float*)d_in[3];
    const float* a1s   = (const float*)d_in[4];
    const float* a1d   = (const float*)d_in[5];
    const float* b1    = (const float*)d_in[6];
    const float* W2    = (const float*)d_in[7];
    const float* a2s   = (const float*)d_in[8];
    const float* a2d   = (const float*)d_in[9];
    const float* b2    = (const float*)d_in[10];
    const float* Wm1   = (const float*)d_in[11];
    const float* bm1   = (const float*)d_in[12];
    const float* Wm2   = (const float*)d_in[13];
    const float* bm2   = (const float*)d_in[14];
    const float* Wf    = (const float*)d_in[15];
    const float* bfv   = (const float*)d_in[16];
    const float* Wc    = (const float*)d_in[17];
    const float* bc    = (const float*)d_in[18];
    float* out = (float*)d_out;

    size_t off = 0;
    auto alloc = [&](size_t bytes) { size_t o = off; off = (off + bytes + 255) & ~(size_t)255; return o; };
    char* ws = (char*)d_ws;
    // big 2-pass buffers (aliased aggressively)
    unsigned short* xbuf2  = (unsigned short*)(ws + alloc((size_t)2 * M_PAD * KPAD_G * 2)); // 82.8 MB; later reused as h1x2
    unsigned short* hraw2  = (unsigned short*)(ws + alloc((size_t)2 * M_PAD * F1 * 2));     // 51.8 MB; early: MLP split-K partials
    unsigned short* w1t    = (unsigned short*)(ws + alloc((size_t)F1 * KPAD_G * 2));
    unsigned short* w2t    = (unsigned short*)(ws + alloc((size_t)F1 * F1 * 2));
    unsigned short* wm1t   = (unsigned short*)(ws + alloc((size_t)128 * KPAD_G * 2));
    unsigned short* wm2t   = (unsigned short*)(ws + alloc((size_t)128 * 128 * 2));
    unsigned short* t_bf   = (unsigned short*)(ws + alloc((size_t)M_PAD * 128 * 2));
    float*  alpha  = (float*) (ws + alloc((size_t)2 * E_TOT * HEADS * 4));   // alpha, then w (in-place)
    float2* minv   = (float2*)(ws + alloc((size_t)2 * N_NODESC * HEADS * 8));
    float*  es     = (float*) (ws + alloc((size_t)2 * N_NODESC * HEADS * 4));
    float*  edv    = (float*) (ws + alloc((size_t)2 * N_NODESC * HEADS * 4));
    int*    cnt    = (int*)   (ws + alloc((size_t)N_NODESC * 4));
    int*    rowp   = (int*)   (ws + alloc((size_t)(N_NODESC + 16) * 4));
    int*    cursor = (int*)   (ws + alloc((size_t)N_NODESC * 4));
    int*    colsrc = (int*)   (ws + alloc((size_t)E_TOT * 4));
    int*    dstof  = (int*)   (ws + alloc((size_t)E_TOT * 4));
    float*  gx01   = (float*) (ws + alloc((size_t)2 * M_PAD * 128 * 4));
    float*  gx2    = (float*) (ws + alloc((size_t)M_PAD * 128 * 4));
    float*  gsum   = (float*) (ws + alloc((size_t)384 * 4));
    unsigned short* h1x2 = xbuf2;                    // alias: xbuf2 dead after L1 GEMM
    float* gxpart = (float*)hraw2;                   // alias: MLP partials before L1 GEMM writes hraw2
    (void)ws_size; (void)in_sizes; (void)n_in; (void)out_size;

    hipMemsetAsync(cnt, 0, (size_t)N_NODESC * 4, stream);
    hipMemsetAsync(gsum, 0, 384 * 4, stream);

    convert0_k  <<<N_NODESC, 256, 0, stream>>>(x, xbuf2);
    convert_aug_k<<<N_NODESC, 256, 0, stream>>>(x, noise, xbuf2);

    transpose_bf_k<<<dim3(40, 64), 256, 0, stream>>>(W1,  w1t,  NUM_GENE, F1,  KPAD_G);
    transpose_bf_k<<<dim3(40, 40), 256, 0, stream>>>(W2,  w2t,  F1,       F1,  F1);
    transpose_bf_k<<<dim3(4, 64),  256, 0, stream>>>(Wm1, wm1t, NUM_GENE, 128, KPAD_G);
    transpose_bf_k<<<dim3(4, 4),   256, 0, stream>>>(Wm2, wm2t, 128,      128, 128);

    hist_k   <<<(E_TOT + 255) / 256, 256, 0, stream>>>(ei, cnt);
    scan_k   <<<1, 1024, 0, stream>>>(cnt, rowp, cursor);
    scatter_k<<<(E_TOT + 255) / 256, 256, 0, stream>>>(ei, cursor, colsrc, dstof);

    // MLP branch (must finish with gxpart/hraw2 before L1 GEMM; reads xbuf2 slab 0)
    gemm2<2,0,0><<<RT_TILES * 4, 256, 0, stream>>>(xbuf2, KPAD_G, wm1t, KPAD_G,
        nullptr, gxpart, 128, 16, 1, N_NODESC, 4, M_PAD * 128);
    splitred_k<<<1250, 256, 0, stream>>>(gxpart, bm1, t_bf);
    gemm2<1,1,0><<<RT_TILES, 256, 0, stream>>>(t_bf, 128, wm2t, 128,
        bm2, gx2, 128, 4, 1, N_NODESC, 1, 0);

    // ---- combined 2-pass GAT pipeline ----
    // L1 GEMM: [2*M_PAD] x F1
    gemm2<0,0,0><<<MT2 * 10, 256, 0, stream>>>(xbuf2, KPAD_G, w1t, KPAD_G,
        nullptr, hraw2, F1, 64, 10, N_NODESC, 1, 0);
    escores2_k<<<N_NODESC, 320, 0, stream>>>(hraw2, a1s, a1d, es, edv);
    alpha_k <<<(2 * E_TOT + 255) / 256, 256, 0, stream>>>(colsrc, dstof, es, edv, alpha);
    nodems_k<<<(2 * N_NODESC * HEADS + 255) / 256, 256, 0, stream>>>(rowp, alpha, minv);
    wexp_k  <<<(2 * E_TOT + 255) / 256, 256, 0, stream>>>(dstof, minv, alpha);
    agg1_k  <<<N_NODESC, 320, 0, stream>>>(rowp, colsrc, alpha, hraw2, b1, h1x2);

    // L2 GEMM: [2*M_PAD] x F1  (A = h1x2 in xbuf2 region, C = hraw2)
    gemm2<0,0,0><<<MT2 * 10, 256, 0, stream>>>(h1x2, F1, w2t, F1,
        nullptr, hraw2, F1, 40, 10, N_NODESC, 1, 0);
    escores2_k<<<N_NODESC, 320, 0, stream>>>(hraw2, a2s, a2d, es, edv);
    alpha_k <<<(2 * E_TOT + 255) / 256, 256, 0, stream>>>(colsrc, dstof, es, edv, alpha);
    nodems_k<<<(2 * N_NODESC * HEADS + 255) / 256, 256, 0, stream>>>(rowp, alpha, minv);
    wexp_k  <<<(2 * E_TOT + 255) / 256, 256, 0, stream>>>(dstof, minv, alpha);
    agg2_k  <<<N_NODESC, 320, 0, stream>>>(rowp, colsrc, alpha, hraw2, b2, gx01);

    colsum_k<<<120, 256, 0, stream>>>(gx01, gx2, gsum);
    loss_k  <<<1, 128, 0, stream>>>(gsum, out + 1920000);

    proj_k<<<dim3(2500, 3), 256, 0, stream>>>(gx01, gx2, Wf, bfv, Wc, bc, out);
}

// Round 5
// 760.468 us; speedup vs baseline: 1.8509x; 1.0507x over previous
//
#include <hip/hip_runtime.h>
#include <hip/hip_bf16.h>

// ---------------- problem constants ----------------
#define N_NODESC 10000
#define M_PAD    10112          // 79 * 128
#define RT_TILES 79
#define NUM_GENE 2000
#define KPAD_G   2048
#define N_EDGESC 160000
#define E_TOT    170000         // + self loops
#define HEADS    10
#define F1       1280           // HEADS*128
#define LATENTC  128
#define LOWERC   64
#define CLUST    15

typedef __attribute__((ext_vector_type(8))) short   short8;
typedef __attribute__((ext_vector_type(4))) float   f32x4;
typedef __attribute__((ext_vector_type(4))) unsigned short ushort4_;

__device__ __forceinline__ float bf2f(unsigned short u){
    unsigned int x = ((unsigned int)u) << 16;
    return __builtin_bit_cast(float, x);
}
__device__ __forceinline__ unsigned short f2bf(float f){
    __hip_bfloat16 h = __float2bfloat16(f);
    return __builtin_bit_cast(unsigned short, h);
}
__device__ __forceinline__ void gload16(const void* g, void* l) {
    __builtin_amdgcn_global_load_lds((const __attribute__((address_space(1))) void*)g,
                                     (__attribute__((address_space(3))) void*)l, 16, 0, 0);
}

// ======== 256x256 bf16 MFMA GEMM, counted-vmcnt dbuf pipeline (T3/T4), XCD swizzle ====
// C[rows x N] = A[rows x K] * BT[N x K]^T, rows = 2*M_PAD slabs, K = NK*32, N = NT*256.
// Pad rows (per M_PAD slab, >= M_real) written as 0. No bias/relu (GAT GEMMs).
template<int OMODE>   // 0 bf16 out, 1 f32 out
__global__ __launch_bounds__(512, 2)
void gemm256(const unsigned short* __restrict__ A, int lda,
             const unsigned short* __restrict__ BT, int ldb,
             void* __restrict__ Cp, int ldc,
             int NK, int NT, int M_real)
{
    __shared__ short smem[32768];   // 2 buf x (A 256x32 + B 256x32) = 64 KiB

    const int nwg = gridDim.x;
    const int q = nwg >> 3, r = nwg & 7;
    const int xcd = blockIdx.x & 7, idx = blockIdx.x >> 3;
    const int wgid = (xcd < r ? xcd * (q + 1) : r * (q + 1) + (xcd - r) * q) + idx;
    const int bm = wgid / NT, bn = wgid - bm * NT;

    const int t = threadIdx.x, w = t >> 6, lane = t & 63;
    const int wr = (w >> 2) * 128, wc = (w & 3) * 64;   // 2M x 4N wave grid
    const int lrow = lane & 15, lq = lane >> 4;

    // staging addresses: 1024 chunks of 16B per matrix, 2 per thread
    const unsigned short* Ag[2];
    const unsigned short* Bg[2];
    int loff[2];
    #pragma unroll
    for (int cc = 0; cc < 2; ++cc) {
        int c = cc * 512 + t;
        int row = c >> 2, slot = c & 3;
        int gk = (slot ^ ((row >> 1) & 3)) << 3;   // pre-swizzled global k (rule 21)
        Ag[cc] = A  + (size_t)(bm * 256 + row) * lda + gk;
        Bg[cc] = BT + (size_t)(bn * 256 + row) * ldb + gk;
        loff[cc] = c * 8;                          // shorts (16B chunks, linear)
    }
    auto stage = [&](int buf, int kt) {
        const int kk = kt * 32;
        short* base = smem + buf * 16384;
        #pragma unroll
        for (int cc = 0; cc < 2; ++cc) {
            gload16(Ag[cc] + kk, base + loff[cc]);
            gload16(Bg[cc] + kk, base + 8192 + loff[cc]);
        }
    };

    f32x4 acc[8][4] = {};
    stage(0, 0);
    if (NK > 1) stage(1, 1);
    for (int kt = 0; kt < NK; ++kt) {
        const int cur = kt & 1;
        // counted wait: keep next tile's 4 loads in flight across the barrier (T4)
        if (kt + 1 < NK) { asm volatile("s_waitcnt vmcnt(4)" ::: "memory"); }
        else             { asm volatile("s_waitcnt vmcnt(0)" ::: "memory"); }
        __builtin_amdgcn_sched_barrier(0);
        __builtin_amdgcn_s_barrier();
        __builtin_amdgcn_sched_barrier(0);

        const short* As = smem + cur * 16384;
        const short* Bs = As + 8192;
        short8 af[8], bf_[4];
        #pragma unroll
        for (int mi = 0; mi < 8; ++mi) {
            int rr = wr + mi * 16 + lrow;
            af[mi] = *(const short8*)(&As[rr * 32 + ((lq ^ ((rr >> 1) & 3)) << 3)]);
        }
        #pragma unroll
        for (int ni = 0; ni < 4; ++ni) {
            int rr = wc + ni * 16 + lrow;
            bf_[ni] = *(const short8*)(&Bs[rr * 32 + ((lq ^ ((rr >> 1) & 3)) << 3)]);
        }
        __builtin_amdgcn_s_setprio(1);
        #pragma unroll
        for (int mi = 0; mi < 8; ++mi)
            #pragma unroll
            for (int ni = 0; ni < 4; ++ni)
                acc[mi][ni] = __builtin_amdgcn_mfma_f32_16x16x32_bf16(af[mi], bf_[ni], acc[mi][ni], 0, 0, 0);
        __builtin_amdgcn_s_setprio(0);
        __builtin_amdgcn_sched_barrier(0);
        __builtin_amdgcn_s_barrier();     // all waves done reading buf[cur]
        __builtin_amdgcn_sched_barrier(0);
        if (kt + 2 < NK) stage(cur, kt + 2);   // overwrite buf[cur]; flies through next iter
    }

    // epilogue: C/D layout col=lane&15, row=(lane>>4)*4+q (m89)
    #pragma unroll
    for (int mi = 0; mi < 8; ++mi) {
        #pragma unroll
        for (int ni = 0; ni < 4; ++ni) {
            int gcol = bn * 256 + wc + ni * 16 + lrow;
            #pragma unroll
            for (int qq = 0; qq < 4; ++qq) {
                int grow = bm * 256 + wr + mi * 16 + lq * 4 + qq;
                float val = acc[mi][ni][qq];
                int rslab = grow >= M_PAD ? grow - M_PAD : grow;
                if (rslab >= M_real) val = 0.f;
                if constexpr (OMODE == 0)
                    ((unsigned short*)Cp)[(size_t)grow * ldc + gcol] = f2bf(val);
                else
                    ((float*)Cp)[(size_t)grow * ldc + gcol] = val;
            }
        }
    }
}

// ---------------- 128x128 bf16 GEMM (MLP path), dbuf 2-phase ----------------
template<int OMODE, int BIAS, int RELU>   // OMODE: 1 f32 out, 2 f32 split-K partial
__global__ __launch_bounds__(256)
void gemm2(const unsigned short* __restrict__ A, int lda,
           const unsigned short* __restrict__ BT, int ldb,
           const float* __restrict__ bias,
           void* __restrict__ Cp, int ldc,
           int KT, int NT, int M_real, int NSPLIT, int slab)
{
    __shared__ short smem[16384];

    const int nwg = gridDim.x;
    const int q = nwg >> 3, r = nwg & 7;
    const int xcd = blockIdx.x & 7, idx = blockIdx.x >> 3;
    const int wgid = (xcd < r ? xcd * (q + 1) : r * (q + 1) + (xcd - r) * q) + idx;
    const int tot_mn = nwg / NSPLIT;
    const int s  = wgid / tot_mn;
    const int mn = wgid - s * tot_mn;
    const int bm = mn / NT, bn = mn - bm * NT;

    const int t = threadIdx.x, w = t >> 6, lane = t & 63;
    const int wr = (w >> 1) * 64, wc = (w & 1) * 64;
    const int lrow = lane & 15, lq = lane >> 4;

    const int kt_beg = s * KT, kt_end = kt_beg + KT;

    const unsigned short* Ag[2];
    const unsigned short* Bg[2];
    int lds_off[2];
    #pragma unroll
    for (int cc = 0; cc < 2; ++cc) {
        int c = cc * 256 + t;
        int row = c >> 2, slot = c & 3;
        int gk = (slot ^ ((row >> 1) & 3)) << 3;
        Ag[cc] = A  + (size_t)(bm * 128 + row) * lda + gk;
        Bg[cc] = BT + (size_t)(bn * 128 + row) * ldb + gk;
        lds_off[cc] = cc * 2048 + w * 512 + lane * 8;
    }

    auto stage = [&](int buf, int kt) {
        const int kk = kt * 32;
        #pragma unroll
        for (int cc = 0; cc < 2; ++cc) {
            gload16(Ag[cc] + kk, smem + buf * 8192 + lds_off[cc]);
            gload16(Bg[cc] + kk, smem + buf * 8192 + 4096 + lds_off[cc]);
        }
    };

    f32x4 acc[4][4] = {};
    stage(0, kt_beg);
    __syncthreads();
    int cur = 0;
    for (int kt = kt_beg; kt < kt_end; ++kt) {
        if (kt + 1 < kt_end) stage(cur ^ 1, kt + 1);
        const short* As = smem + cur * 8192;
        const short* Bs = As + 4096;
        short8 af[4], bf_[4];
        #pragma unroll
        for (int mi = 0; mi < 4; ++mi) {
            int rr = wr + mi * 16 + lrow;
            af[mi] = *(const short8*)(&As[rr * 32 + ((lq ^ ((rr >> 1) & 3)) << 3)]);
        }
        #pragma unroll
        for (int ni = 0; ni < 4; ++ni) {
            int rr = wc + ni * 16 + lrow;
            bf_[ni] = *(const short8*)(&Bs[rr * 32 + ((lq ^ ((rr >> 1) & 3)) << 3)]);
        }
        #pragma unroll
        for (int mi = 0; mi < 4; ++mi)
            #pragma unroll
            for (int ni = 0; ni < 4; ++ni)
                acc[mi][ni] = __builtin_amdgcn_mfma_f32_16x16x32_bf16(af[mi], bf_[ni], acc[mi][ni], 0, 0, 0);
        __syncthreads();
        cur ^= 1;
    }

    float* Cf = (float*)Cp + (size_t)s * slab;
    #pragma unroll
    for (int mi = 0; mi < 4; ++mi) {
        #pragma unroll
        for (int ni = 0; ni < 4; ++ni) {
            int gcol = bn * 128 + wc + ni * 16 + lrow;
            #pragma unroll
            for (int qq = 0; qq < 4; ++qq) {
                int grow = bm * 128 + wr + mi * 16 + lq * 4 + qq;
                float val = acc[mi][ni][qq];
                if constexpr (OMODE == 2) {
                    Cf[(size_t)grow * ldc + gcol] = val;
                } else {
                    if constexpr (BIAS) val += bias[gcol];
                    if constexpr (RELU) val = fmaxf(val, 0.f);
                    if (grow >= M_real) val = 0.f;
                    ((float*)Cp)[(size_t)grow * ldc + gcol] = val;
                }
            }
        }
    }
}

// ---------------- x -> bf16 slab0 AND x_aug -> bf16 slab1 (x read once) ----------------
__global__ void convert_both_k(const float* __restrict__ x, const float* __restrict__ noise,
                               unsigned short* __restrict__ out)
{
    __shared__ float sred[4];
    __shared__ float srn;
    int row = blockIdx.x, t = threadIdx.x;
    int kc = t * 8;
    f32x4 n0 = {}, n1 = {};
    float ss = 0.f;
    if (t < 250) {
        n0 = *(const f32x4*)(noise + (size_t)row * NUM_GENE + kc);
        n1 = *(const f32x4*)(noise + (size_t)row * NUM_GENE + kc + 4);
        ss = n0.x*n0.x + n0.y*n0.y + n0.z*n0.z + n0.w*n0.w
           + n1.x*n1.x + n1.y*n1.y + n1.z*n1.z + n1.w*n1.w;
    }
    for (int off = 32; off; off >>= 1) ss += __shfl_down(ss, off);
    if ((t & 63) == 0) sred[t >> 6] = ss;
    __syncthreads();
    if (t == 0) srn = 1.f / fmaxf(sqrtf(sred[0] + sred[1] + sred[2] + sred[3]), 1e-12f);
    __syncthreads();
    if (t >= 250) return;
    float rn = srn;
    f32x4 a0 = *(const f32x4*)(x + (size_t)row * NUM_GENE + kc);
    f32x4 a1 = *(const f32x4*)(x + (size_t)row * NUM_GENE + kc + 4);
    short8 v0, v1;
    #pragma unroll
    for (int i = 0; i < 4; ++i) {
        v0[i]     = (short)f2bf(a0[i]);
        v0[4 + i] = (short)f2bf(a1[i]);
        v1[i]     = (short)f2bf(a0[i] + n0[i] * rn);
        v1[4 + i] = (short)f2bf(a1[i] + n1[i] * rn);
    }
    *(short8*)(out + (size_t)row * KPAD_G + kc) = v0;
    *(short8*)(out + (size_t)(M_PAD + row) * KPAD_G + kc) = v1;
}

// ---------------- split-K reduce + bias + relu -> bf16 ----------------
__global__ void splitred_k(const float* __restrict__ part, const float* __restrict__ bm1,
                           unsigned short* __restrict__ out)
{
    int gid = blockIdx.x * 256 + threadIdx.x;
    int row = gid >> 5, c4 = (gid & 31) * 4;
    if (row >= N_NODESC) return;
    size_t o = (size_t)row * 128 + c4;
    const size_t slab = (size_t)M_PAD * 128;
    f32x4 v = *(const f32x4*)(part + o) + *(const f32x4*)(part + slab + o)
            + *(const f32x4*)(part + 2 * slab + o) + *(const f32x4*)(part + 3 * slab + o);
    f32x4 b = *(const f32x4*)(bm1 + c4);
    ushort4_ u;
    u.x = f2bf(fmaxf(v.x + b.x, 0.f)); u.y = f2bf(fmaxf(v.y + b.y, 0.f));
    u.z = f2bf(fmaxf(v.z + b.z, 0.f)); u.w = f2bf(fmaxf(v.w + b.w, 0.f));
    *(ushort4_*)(out + o) = u;
}

// ---------------- transpose + fp32->bf16 (+K pad zeroed) ----------------
__global__ void transpose_bf_k(const float* __restrict__ in, unsigned short* __restrict__ out,
                               int R, int C, int Kpad)
{
    __shared__ float tile[32][33];
    int tx = threadIdx.x & 31, ty = threadIdx.x >> 5;
    int c0 = blockIdx.x * 32, r0 = blockIdx.y * 32;
    #pragma unroll
    for (int i = 0; i < 4; ++i) {
        int r = r0 + ty + i * 8, c = c0 + tx;
        tile[ty + i * 8][tx] = (r < R && c < C) ? in[(size_t)r * C + c] : 0.f;
    }
    __syncthreads();
    #pragma unroll
    for (int i = 0; i < 4; ++i) {
        int c = c0 + ty + i * 8;
        int r = r0 + tx;
        if (c < C && r < Kpad) out[(size_t)c * Kpad + r] = f2bf(tile[tx][ty + i * 8]);
    }
}

// ---------------- CSR build by dst ----------------
__global__ void hist_k(const int* __restrict__ ei, int* __restrict__ cnt)
{
    int e = blockIdx.x * 256 + threadIdx.x;
    if (e >= E_TOT) return;
    int d = (e < N_EDGESC) ? ei[N_EDGESC + e] : (e - N_EDGESC);
    atomicAdd(&cnt[d], 1);
}

__global__ void scan_k(const int* __restrict__ cnt, int* __restrict__ rowp, int* __restrict__ cursor)
{
    __shared__ int buf[1024];
    int t = threadIdx.x;
    int loc[10];
    int s = 0, base = t * 10;
    #pragma unroll
    for (int i = 0; i < 10; ++i) {
        int idx = base + i;
        int v = (idx < N_NODESC) ? cnt[idx] : 0;
        loc[i] = v; s += v;
    }
    buf[t] = s; __syncthreads();
    for (int off = 1; off < 1024; off <<= 1) {
        int tmp = (t >= off) ? buf[t - off] : 0;
        __syncthreads();
        buf[t] += tmp;
        __syncthreads();
    }
    int run = buf[t] - s;
    #pragma unroll
    for (int i = 0; i < 10; ++i) {
        int idx = base + i;
        if (idx < N_NODESC) { rowp[idx] = run; cursor[idx] = run; run += loc[i]; }
    }
    if (t == 1023) rowp[N_NODESC] = buf[1023];
}

__global__ void scatter_k(const int* __restrict__ ei, int* __restrict__ cursor,
                          int* __restrict__ col_src, int* __restrict__ dst_of)
{
    int e = blockIdx.x * 256 + threadIdx.x;
    if (e >= E_TOT) return;
    int s, d;
    if (e < N_EDGESC) { s = ei[e]; d = ei[N_EDGESC + e]; } else { s = d = e - N_EDGESC; }
    int pos = atomicAdd(&cursor[d], 1);
    col_src[pos] = s;
    dst_of[pos] = d;
}

// ---------------- attention scores for both passes; 320 thr = 2 nodes ----------------
__global__ void escores2_k(const unsigned short* __restrict__ h,
                           const float* __restrict__ a_src, const float* __restrict__ a_dst,
                           float* __restrict__ e_s, float* __restrict__ e_d)
{
    int t = threadIdx.x;
    int half = (t >= 160);
    int tl = t - half * 160;
    int node2 = blockIdx.x * 2 + half;
    int p = node2 >= N_NODESC;
    int n = node2 - p * N_NODESC;
    int hh = tl >> 4, c = tl & 15;
    int off = hh * 128 + c * 8;
    short8 v = *(const short8*)(h + (size_t)(p * M_PAD + n) * F1 + off);
    float ps = 0.f, pd = 0.f;
    #pragma unroll
    for (int j = 0; j < 8; ++j) {
        float f = bf2f((unsigned short)v[j]);
        ps += f * a_src[off + j];
        pd += f * a_dst[off + j];
    }
    #pragma unroll
    for (int m = 1; m < 16; m <<= 1) {
        ps += __shfl_xor(ps, m, 16);
        pd += __shfl_xor(pd, m, 16);
    }
    if (c == 0) { e_s[node2 * HEADS + hh] = ps; e_d[node2 * HEADS + hh] = pd; }
}

// ---------------- per-edge alpha (gather-once), both passes ----------------
__global__ void alpha_k(const int* __restrict__ colsrc, const int* __restrict__ dstof,
                        const float* __restrict__ e_s, const float* __restrict__ e_d,
                        float* __restrict__ alpha)
{
    int gid = blockIdx.x * 256 + threadIdx.x;
    if (gid >= 2 * E_TOT) return;
    int p = gid >= E_TOT;
    int e = gid - p * E_TOT;
    int s = colsrc[e], d = dstof[e];
    const float* er = e_s + (size_t)(p * N_NODESC + s) * HEADS;
    const float* dr = e_d + (size_t)(p * N_NODESC + d) * HEADS;
    float* o = alpha + (size_t)gid * HEADS;
    #pragma unroll
    for (int h = 0; h < HEADS; ++h) {
        float a = er[h] + dr[h];
        o[h] = a >= 0.f ? a : 0.2f * a;
    }
}

// ---------------- per-(pass,node,head) online max/sum ----------------
__global__ void nodems_k(const int* __restrict__ rowp, const float* __restrict__ alpha,
                         float2* __restrict__ minv)
{
    int gid = blockIdx.x * 256 + threadIdx.x;
    if (gid >= 2 * N_NODESC * HEADS) return;
    int p = gid >= N_NODESC * HEADS;
    int rr = gid - p * N_NODESC * HEADS;
    int n = rr / HEADS, hh = rr - n * HEADS;
    int beg = rowp[n], end = rowp[n + 1];
    size_t base = (size_t)p * E_TOT;
    float m = -1e30f, ssum = 0.f;
    for (int e = beg; e < end; ++e) {
        float a = alpha[(base + e) * HEADS + hh];
        if (a > m) { ssum = ssum * __expf(m - a) + 1.f; m = a; }
        else ssum += __expf(a - m);
    }
    float2 qo; qo.x = m; qo.y = 1.f / ssum;
    minv[gid] = qo;
}

// ---------------- per-edge softmax weight, in-place on alpha ----------------
__global__ void wexp_k(const int* __restrict__ dstof, const float2* __restrict__ minv,
                       float* __restrict__ alpha)
{
    int gid = blockIdx.x * 256 + threadIdx.x;
    if (gid >= 2 * E_TOT) return;
    int p = gid >= E_TOT;
    int e = gid - p * E_TOT;
    int d = dstof[e];
    const float2* mv = minv + (size_t)(p * N_NODESC + d) * HEADS;
    float* wv = alpha + (size_t)gid * HEADS;
    #pragma unroll
    for (int h = 0; h < HEADS; ++h) {
        float2 qv = mv[h];
        wv[h] = __expf(wv[h] - qv.x) * qv.y;
    }
}

// ---------------- layer1 aggregate (concat) -> bf16; both passes ----------------
__global__ void agg1_k(const int* __restrict__ rowp, const int* __restrict__ colsrc,
                       const float* __restrict__ w_all,
                       const unsigned short* __restrict__ h, const float* __restrict__ b1,
                       unsigned short* __restrict__ out)
{
    int t = threadIdx.x;
    int half = (t >= 160);
    int tl = t - half * 160;
    int node2 = blockIdx.x * 2 + half;
    int p = node2 >= N_NODESC;
    int n = node2 - p * N_NODESC;
    int f0 = tl * 8, hh = tl >> 4;
    int beg = rowp[n], end = rowp[n + 1];
    const unsigned short* hb = h + (size_t)p * M_PAD * F1;
    const float* wb = w_all + (size_t)p * E_TOT * HEADS;
    float acc[8] = {};
    for (int e = beg; e < end; ++e) {
        int s = colsrc[e];
        float wv = wb[(size_t)e * HEADS + hh];
        short8 rv = *(const short8*)(hb + (size_t)s * F1 + f0);
        #pragma unroll
        for (int j = 0; j < 8; ++j) acc[j] += wv * bf2f((unsigned short)rv[j]);
    }
    short8 o;
    #pragma unroll
    for (int j = 0; j < 8; ++j) o[j] = (short)f2bf(fmaxf(acc[j] + b1[f0 + j], 0.f));
    *(short8*)(out + (size_t)(p * M_PAD + n) * F1 + f0) = o;
}

// ---------------- layer2 aggregate (head mean) -> f32; both passes ----------------
__global__ void agg2_k(const int* __restrict__ rowp, const int* __restrict__ colsrc,
                       const float* __restrict__ w_all,
                       const unsigned short* __restrict__ h, const float* __restrict__ b2,
                       float* __restrict__ out)
{
    __shared__ float red[2][160][8];
    int t = threadIdx.x;
    int half = (t >= 160);
    int tl = t - half * 160;
    int node2 = blockIdx.x * 2 + half;
    int p = node2 >= N_NODESC;
    int n = node2 - p * N_NODESC;
    int f0 = tl * 8, hh = tl >> 4;
    int beg = rowp[n], end = rowp[n + 1];
    const unsigned short* hb = h + (size_t)p * M_PAD * F1;
    const float* wb = w_all + (size_t)p * E_TOT * HEADS;
    float acc[8] = {};
    for (int e = beg; e < end; ++e) {
        int s = colsrc[e];
        float wv = wb[(size_t)e * HEADS + hh];
        short8 rv = *(const short8*)(hb + (size_t)s * F1 + f0);
        #pragma unroll
        for (int j = 0; j < 8; ++j) acc[j] += wv * bf2f((unsigned short)rv[j]);
    }
    #pragma unroll
    for (int j = 0; j < 8; ++j) red[half][tl][j] = acc[j];
    __syncthreads();
    if (tl < 128) {
        int c = tl >> 3, j = tl & 7;
        float s = 0.f;
        #pragma unroll
        for (int hq = 0; hq < HEADS; ++hq) s += red[half][hq * 16 + c][j];
        out[(size_t)(p * M_PAD + n) * LATENTC + tl] = fmaxf(s * 0.1f + b2[tl], 0.f);
    }
}

// ---------------- column sums for pooling ----------------
__global__ void colsum_k(const float* __restrict__ g01, const float* __restrict__ g2,
                         float* __restrict__ gsum)
{
    int v = blockIdx.x / 40, b = blockIdx.x % 40;
    const float* src = (v == 0) ? g01 : (v == 1) ? g01 + (size_t)M_PAD * 128 : g2;
    int t = threadIdx.x, col = t & 127, ro = t >> 7;
    int rend = min((b + 1) * 250, N_NODESC);
    float acc = 0.f;
    for (int r = b * 250 + ro; r < rend; r += 2) acc += src[(size_t)r * 128 + col];
    __shared__ float part[256];
    part[t] = acc; __syncthreads();
    if (t < 128) atomicAdd(&gsum[v * 128 + col], part[t] + part[t + 128]);
}

// ---------------- contrastive loss scalar ----------------
__global__ void loss_k(const float* __restrict__ gsum, float* __restrict__ out)
{
    int t = threadIdx.x;   // 128
    float g0 = gsum[t] * 1e-4f, g1 = gsum[128 + t] * 1e-4f, g2 = gsum[256 + t] * 1e-4f;
    float d01 = g0 * g1, d02 = g0 * g2, d12 = g1 * g2;
    for (int off = 32; off; off >>= 1) {
        d01 += __shfl_down(d01, off); d02 += __shfl_down(d02, off); d12 += __shfl_down(d12, off);
    }
    __shared__ float s[3][2];
    if ((t & 63) == 0) { int w = t >> 6; s[0][w] = d01; s[1][w] = d02; s[2][w] = d12; }
    __syncthreads();
    if (t == 0) {
        float a01 = (s[0][0] + s[0][1]) * 5.f;
        float a02 = (s[1][0] + s[1][1]) * 5.f;
        float a12 = (s[2][0] + s[2][1]) * 5.f;
        float m = fmaxf(a01, fmaxf(a02, a12));
        float se = expf(a01 - m) + expf(a02 - m) + expf(a12 - m);
        *out = -((a01 - m) - logf(se)) / 2.302585092994046f;
    }
}

// ---------------- projection heads ----------------
__global__ void proj_k(const float* __restrict__ g01, const float* __restrict__ g2,
                       const float* __restrict__ Wf, const float* __restrict__ bfv,
                       const float* __restrict__ Wc, const float* __restrict__ bc,
                       float* __restrict__ out)
{
    __shared__ float rowb[4][128];
    int m = blockIdx.y;
    const float* gx = (m == 0) ? g01 : (m == 1) ? g01 + (size_t)M_PAD * 128 : g2;
    float* out_node = out + (size_t)m * 640000;
    float* out_c = (m == 0) ? out + 1920001 : (m == 1) ? out + 2070001 : nullptr;
    int wid = threadIdx.x >> 6, l = threadIdx.x & 63;
    int n = blockIdx.x * 4 + wid;
    if (n >= N_NODESC) return;
    rowb[wid][l]      = gx[(size_t)n * 128 + l];
    rowb[wid][l + 64] = gx[(size_t)n * 128 + 64 + l];
    float acc = bfv[l];
    #pragma unroll 8
    for (int k = 0; k < 128; ++k) acc += rowb[wid][k] * Wf[k * 64 + l];
    out_node[(size_t)n * 64 + l] = acc;
    if (out_c != nullptr && l < CLUST) {
        float a2 = bc[l];
        #pragma unroll 8
        for (int k = 0; k < 128; ++k) a2 += rowb[wid][k] * Wc[k * CLUST + l];
        out_c[(size_t)l * N_NODESC + n] = a2;
    }
}

// ---------------- host ----------------
extern "C" void kernel_launch(void* const* d_in, const int* in_sizes, int n_in,
                              void* d_out, int out_size, void* d_ws, size_t ws_size,
                              hipStream_t stream)
{
    const float* x     = (const float*)d_in[0];
    const int*   ei    = (const int*)  d_in[1];
    const float* noise = (const float*)d_in[2];
    const float* W1    = (const float*)d_in[3];
    const float* a1s   = (const float*)d_in[4];
    const float* a1d   = (const float*)d_in[5];
    const float* b1    = (const float*)d_in[6];
    const float* W2    = (const float*)d_in[7];
    const float* a2s   = (const float*)d_in[8];
    const float* a2d   = (const float*)d_in[9];
    const float* b2    = (const float*)d_in[10];
    const float* Wm1   = (const float*)d_in[11];
    const float* bm1   = (const float*)d_in[12];
    const float* Wm2   = (const float*)d_in[13];
    const float* bm2   = (const float*)d_in[14];
    const float* Wf    = (const float*)d_in[15];
    const float* bfv   = (const float*)d_in[16];
    const float* Wc    = (const float*)d_in[17];
    const float* bc    = (const float*)d_in[18];
    float* out = (float*)d_out;

    size_t off = 0;
    auto alloc = [&](size_t bytes) { size_t o = off; off = (off + bytes + 255) & ~(size_t)255; return o; };
    char* ws = (char*)d_ws;
    unsigned short* xbuf2  = (unsigned short*)(ws + alloc((size_t)2 * M_PAD * KPAD_G * 2)); // later h1x2
    unsigned short* hraw2  = (unsigned short*)(ws + alloc((size_t)2 * M_PAD * F1 * 2));     // early: MLP partials
    unsigned short* w1t    = (unsigned short*)(ws + alloc((size_t)F1 * KPAD_G * 2));
    unsigned short* w2t    = (unsigned short*)(ws + alloc((size_t)F1 * F1 * 2));
    unsigned short* wm1t   = (unsigned short*)(ws + alloc((size_t)128 * KPAD_G * 2));
    unsigned short* wm2t   = (unsigned short*)(ws + alloc((size_t)128 * 128 * 2));
    unsigned short* t_bf   = (unsigned short*)(ws + alloc((size_t)M_PAD * 128 * 2));
    float*  alpha  = (float*) (ws + alloc((size_t)2 * E_TOT * HEADS * 4));
    float2* minv   = (float2*)(ws + alloc((size_t)2 * N_NODESC * HEADS * 8));
    float*  es     = (float*) (ws + alloc((size_t)2 * N_NODESC * HEADS * 4));
    float*  edv    = (float*) (ws + alloc((size_t)2 * N_NODESC * HEADS * 4));
    int*    cnt    = (int*)   (ws + alloc((size_t)N_NODESC * 4));
    int*    rowp   = (int*)   (ws + alloc((size_t)(N_NODESC + 16) * 4));
    int*    cursor = (int*)   (ws + alloc((size_t)N_NODESC * 4));
    int*    colsrc = (int*)   (ws + alloc((size_t)E_TOT * 4));
    int*    dstof  = (int*)   (ws + alloc((size_t)E_TOT * 4));
    float*  gx01   = (float*) (ws + alloc((size_t)2 * M_PAD * 128 * 4));
    float*  gx2    = (float*) (ws + alloc((size_t)M_PAD * 128 * 4));
    float*  gsum   = (float*) (ws + alloc((size_t)384 * 4));
    unsigned short* h1x2 = xbuf2;
    float* gxpart = (float*)hraw2;
    (void)ws_size; (void)in_sizes; (void)n_in; (void)out_size;

    hipMemsetAsync(cnt, 0, (size_t)N_NODESC * 4, stream);
    hipMemsetAsync(gsum, 0, 384 * 4, stream);

    convert_both_k<<<N_NODESC, 256, 0, stream>>>(x, noise, xbuf2);

    transpose_bf_k<<<dim3(40, 64), 256, 0, stream>>>(W1,  w1t,  NUM_GENE, F1,  KPAD_G);
    transpose_bf_k<<<dim3(40, 40), 256, 0, stream>>>(W2,  w2t,  F1,       F1,  F1);
    transpose_bf_k<<<dim3(4, 64),  256, 0, stream>>>(Wm1, wm1t, NUM_GENE, 128, KPAD_G);
    transpose_bf_k<<<dim3(4, 4),   256, 0, stream>>>(Wm2, wm2t, 128,      128, 128);

    hist_k   <<<(E_TOT + 255) / 256, 256, 0, stream>>>(ei, cnt);
    scan_k   <<<1, 1024, 0, stream>>>(cnt, rowp, cursor);
    scatter_k<<<(E_TOT + 255) / 256, 256, 0, stream>>>(ei, cursor, colsrc, dstof);

    // MLP branch (gxpart aliases hraw2; finishes before L1 GEMM writes hraw2)
    gemm2<2,0,0><<<RT_TILES * 4, 256, 0, stream>>>(xbuf2, KPAD_G, wm1t, KPAD_G,
        nullptr, gxpart, 128, 16, 1, N_NODESC, 4, M_PAD * 128);
    splitred_k<<<1250, 256, 0, stream>>>(gxpart, bm1, t_bf);
    gemm2<1,1,0><<<RT_TILES, 256, 0, stream>>>(t_bf, 128, wm2t, 128,
        bm2, gx2, 128, 4, 1, N_NODESC, 1, 0);

    // ---- combined 2-pass GAT pipeline ----
    gemm256<0><<<RT_TILES * 5, 512, 0, stream>>>(xbuf2, KPAD_G, w1t, KPAD_G,
        hraw2, F1, 64, 5, N_NODESC);
    escores2_k<<<N_NODESC, 320, 0, stream>>>(hraw2, a1s, a1d, es, edv);
    alpha_k <<<(2 * E_TOT + 255) / 256, 256, 0, stream>>>(colsrc, dstof, es, edv, alpha);
    nodems_k<<<(2 * N_NODESC * HEADS + 255) / 256, 256, 0, stream>>>(rowp, alpha, minv);
    wexp_k  <<<(2 * E_TOT + 255) / 256, 256, 0, stream>>>(dstof, minv, alpha);
    agg1_k  <<<N_NODESC, 320, 0, stream>>>(rowp, colsrc, alpha, hraw2, b1, h1x2);

    gemm256<0><<<RT_TILES * 5, 512, 0, stream>>>(h1x2, F1, w2t, F1,
        hraw2, F1, 40, 5, N_NODESC);
    escores2_k<<<N_NODESC, 320, 0, stream>>>(hraw2, a2s, a2d, es, edv);
    alpha_k <<<(2 * E_TOT + 255) / 256, 256, 0, stream>>>(colsrc, dstof, es, edv, alpha);
    nodems_k<<<(2 * N_NODESC * HEADS + 255) / 256, 256, 0, stream>>>(rowp, alpha, minv);
    wexp_k  <<<(2 * E_TOT + 255) / 256, 256, 0, stream>>>(dstof, minv, alpha);
    agg2_k  <<<N_NODESC, 320, 0, stream>>>(rowp, colsrc, alpha, hraw2, b2, gx01);

    colsum_k<<<120, 256, 0, stream>>>(gx01, gx2, gsum);
    loss_k  <<<1, 128, 0, stream>>>(gsum, out + 1920000);

    proj_k<<<dim3(2500, 3), 256, 0, stream>>>(gx01, gx2, Wf, bfv, Wc, bc, out);
}